// Round 1
// baseline (382.929 us; speedup 1.0000x reference)
//
#include <hip/hip_runtime.h>
#include <hip/hip_bf16.h>
#include <math.h>

typedef __hip_bfloat16 bf16;

#define NN 50000
#define EE 800000
#define EPB 4096   // edges per block (hist/scatter)
#define NBK 196    // dst buckets = ceil(NN/256); also blocks for hist/scatter
#define BCAP 6144  // max edges per bucket (mean 4096, sd ~64)

__device__ __forceinline__ float b2f(bf16 v) { return __bfloat162float(v); }
__device__ __forceinline__ float rcp_(float x) { return __builtin_amdgcn_rcpf(x); }
__device__ __forceinline__ float sigmoidf_(float x) { return rcp_(1.0f + __expf(-x)); }
__device__ __forceinline__ float tanhf_(float x) {
    float xx = fminf(fmaxf(x, -15.0f), 15.0f);
    float e = __expf(2.0f * xx);
    return (e - 1.0f) * rcp_(e + 1.0f);
}
__device__ __forceinline__ float leakyf_(float x) { return x > 0.0f ? x : 0.2f * x; }
__device__ __forceinline__ unsigned short f2bf(float f) {
    unsigned u = __float_as_uint(f);
    unsigned r = (u + 0x7FFFu + ((u >> 16) & 1u)) >> 16;
    return (unsigned short)r;
}
__device__ __forceinline__ unsigned pack2(float a, float b) {
    return (unsigned)f2bf(a) | ((unsigned)f2bf(b) << 16);
}
__device__ __forceinline__ float lo_(unsigned u) { return __uint_as_float(u << 16); }
__device__ __forceinline__ float hi_(unsigned u) { return __uint_as_float(u & 0xFFFF0000u); }

// weight-pool element offsets (fp32 pool in ws)
#define OFF_W1 0
#define OFF_B1 16384
#define OFF_W2 16512
#define OFF_B2 24704
#define OFF_W3 24768
#define OFF_B3 26816
#define OFF_GATW 26848
#define OFF_GAS 27872
#define OFF_GAD 27904
#define OFF_GAB 27936
#define OFF_WIHF 27968
#define OFF_BIHF 36160
#define OFF_BHHF 36416
#define OFF_WIHB 36672
#define OFF_BIHB 44864
#define OFF_BHHB 45120
#define OFF_GAMMA 45376
#define OFF_BETA 45504
#define OFF_FCW 45632
#define OFF_FCB 46912
#define WTOTAL 46922

struct WSrc { const void* p[20]; };

// ---------------- dtype detection ----------------
__global__ void k_detect(const unsigned short* __restrict__ xraw,
                         const unsigned int* __restrict__ eraw, int* __restrict__ flags) {
    __shared__ int f32f, i64f;
    int t = threadIdx.x;
    if (t == 0) { f32f = 0; i64f = 1; }
    __syncthreads();
    for (int i = t; i < 4096; i += 256) {
        unsigned short u = xraw[i];
        int ex = (u >> 7) & 0xFF;
        if (ex >= 0xC0) atomicOr(&f32f, 1);
        if (eraw[2 * i + 1] != 0u) atomicAnd(&i64f, 0);
    }
    __syncthreads();
    if (t == 0) { flags[0] = f32f; flags[1] = i64f; }
}

// ---------------- weight conversion into fp32 pool ----------------
__global__ void k_cvt_w(WSrc srcs, float* __restrict__ dst, const int* __restrict__ flags,
                        int total) {
    constexpr int WOFF[21] = {OFF_W1,   OFF_B1,   OFF_W2,   OFF_B2,   OFF_W3,   OFF_B3,
                              OFF_GATW, OFF_GAS,  OFF_GAD,  OFF_GAB,  OFF_WIHF, OFF_BIHF,
                              OFF_BHHF, OFF_WIHB, OFF_BIHB, OFF_BHHB, OFF_GAMMA, OFF_BETA,
                              OFF_FCW,  OFF_FCB,  WTOTAL};
    int i = blockIdx.x * 256 + threadIdx.x;
    if (i >= total) return;
    int tn = 0;
#pragma unroll
    for (int j = 1; j < 20; ++j)
        if (i >= WOFF[j]) tn = j;
    int local = i - WOFF[tn];
    if (flags[0]) dst[i] = ((const float*)srcs.p[tn])[local];
    else dst[i] = b2f(((const bf16*)srcs.p[tn])[local]);
}

// ---------------- bucketed CSR build ----------------
// P1: per-edge-block histogram over dst buckets (LDS atomics only)
__global__ __launch_bounds__(256) void k_hist(const void* __restrict__ eraw,
                                              unsigned* __restrict__ gh,
                                              const int* __restrict__ flags) {
    __shared__ int h[256];
    int t = threadIdx.x, b = blockIdx.x;
    h[t] = 0;
    __syncthreads();
    int e0 = b * EPB;
    bool i64 = flags[1] != 0;
    for (int i = t; i < EPB; i += 256) {
        int e = e0 + i;
        if (e < EE) {
            int d = i64 ? (int)((const long long*)eraw)[EE + e] : ((const int*)eraw)[EE + e];
            d = min(max(d, 0), NN - 1);
            atomicAdd(&h[d >> 8], 1);
        }
    }
    __syncthreads();
    gh[b * 256 + t] = (unsigned)h[t];
}

// P2: per-(block,bucket) bases + bucket bases (one block; coalesced reads)
__global__ __launch_bounds__(256) void k_bscan(const unsigned* __restrict__ gh,
                                               unsigned* __restrict__ gh2,
                                               int* __restrict__ bb, int* __restrict__ rptr) {
    __shared__ int s[256];
    int t = threadIdx.x;
    unsigned run = 0;
    for (int blk = 0; blk < NBK; ++blk) {
        unsigned v = gh[blk * 256 + t];
        gh2[blk * 256 + t] = run;  // within-bucket offset of this edge-block
        run += v;
    }
    s[t] = (int)run;
    __syncthreads();
    for (int o = 1; o < 256; o <<= 1) {
        int x = (t >= o) ? s[t - o] : 0;
        __syncthreads();
        s[t] += x;
        __syncthreads();
    }
    bb[t] = s[t] - (int)run;  // exclusive: bucket base (bb[196] lands on EE)
    if (t == 0) rptr[NN] = EE;
}

// P3: scatter (src,dst) pairs into bucket-partitioned array (LDS cursors, window writes)
__global__ __launch_bounds__(256) void k_scatter(const void* __restrict__ eraw,
                                                 const unsigned* __restrict__ gh2,
                                                 const int* __restrict__ bb,
                                                 int2* __restrict__ ebkt,
                                                 const int* __restrict__ flags) {
    __shared__ unsigned cur[256];
    int t = threadIdx.x, b = blockIdx.x;
    cur[t] = gh2[b * 256 + t] + (unsigned)bb[t];
    __syncthreads();
    int e0 = b * EPB;
    bool i64 = flags[1] != 0;
    for (int i = t; i < EPB; i += 256) {
        int e = e0 + i;
        if (e < EE) {
            int sn, d;
            if (i64) {
                sn = (int)((const long long*)eraw)[e];
                d = (int)((const long long*)eraw)[EE + e];
            } else {
                sn = ((const int*)eraw)[e];
                d = ((const int*)eraw)[EE + e];
            }
            sn = min(max(sn, 0), NN - 1);
            d = min(max(d, 0), NN - 1);
            unsigned pos = atomicAdd(&cur[d >> 8], 1u);
            if (pos < (unsigned)EE) ebkt[pos] = make_int2(sn, d);
        }
    }
}

// P4: per-bucket LDS counting sort -> coalesced csr_src segment + rptr/dis
__global__ __launch_bounds__(256) void k_bucket_csr(const int2* __restrict__ ebkt,
                                                    const int* __restrict__ bb,
                                                    int* __restrict__ rptr,
                                                    float* __restrict__ dis,
                                                    int* __restrict__ csr_src) {
    __shared__ int hist[256];
    __shared__ int excl[256];
    __shared__ int cur[256];
    __shared__ int sorted[BCAP];
    int t = threadIdx.x, b = blockIdx.x;
    int s0 = bb[b], s1 = bb[b + 1];
    int len = min(s1 - s0, BCAP);
    hist[t] = 0;
    __syncthreads();
    for (int i = t; i < len; i += 256) atomicAdd(&hist[ebkt[s0 + i].y & 255], 1);
    __syncthreads();
    int v = hist[t];
    excl[t] = v;
    __syncthreads();
    for (int o = 1; o < 256; o <<= 1) {
        int x = (t >= o) ? excl[t - o] : 0;
        __syncthreads();
        excl[t] += x;
        __syncthreads();
    }
    int loc = excl[t] - v;  // local exclusive offset
    int node = b * 256 + t;
    if (node < NN) {
        rptr[node] = s0 + loc;
        dis[node] = rsqrtf((float)(v + 1));
    }
    cur[t] = loc;
    __syncthreads();
    for (int i = t; i < len; i += 256) {
        int2 p = ebkt[s0 + i];
        int pos = atomicAdd(&cur[p.y & 255], 1);
        if (pos < BCAP) sorted[pos] = p.x;
    }
    __syncthreads();
    for (int i = t; i < len; i += 256) csr_src[s0 + i] = sorted[i];
}

// ---------------- LDS-tiled GEMM: C(bf16) = A @ W, optional per-node dis scaling --------
template <int KIN, int KOUT, int MODE, bool SCALE>
__global__ __launch_bounds__(256) void k_tile_mm(const void* __restrict__ A,
                                                 const float* __restrict__ W,
                                                 unsigned* __restrict__ C, int n,
                                                 const int* __restrict__ flags, int want,
                                                 const float* __restrict__ dis) {
    if (want >= 0 && flags[0] != want) return;
    constexpr int BK = 32;
    constexpr int AST = BK + 4;
    constexpr int CPT = KOUT / 16;  // 8 / 4 / 2
    __shared__ float As[64 * AST];
    __shared__ float Ws[BK * KOUT];
    int t = threadIdx.x;
    int jc = t & 15;
    int ng = t >> 4;
    int base = blockIdx.x * 64;
    float acc[4][CPT];
#pragma unroll
    for (int i = 0; i < 4; ++i)
#pragma unroll
        for (int c = 0; c < CPT; ++c) acc[i][c] = 0.f;
    int snode = t >> 2;
    int gnode = min(base + snode, n - 1);
    int koff = (t & 3) * 8;
    for (int k0 = 0; k0 < KIN; k0 += BK) {
        {
            const float4* src = (const float4*)(W + k0 * KOUT);
            float4* dst = (float4*)Ws;
#pragma unroll
            for (int p = 0; p < BK * KOUT / 1024; ++p) dst[t + p * 256] = src[t + p * 256];
        }
        if (MODE == 0) {
            const unsigned* xr = (const unsigned*)A + (size_t)gnode * (KIN / 2) + (k0 + koff) / 2;
            unsigned u0 = xr[0], u1 = xr[1], u2 = xr[2], u3 = xr[3];
            float* d = As + snode * AST + koff;
            d[0] = lo_(u0); d[1] = hi_(u0);
            d[2] = lo_(u1); d[3] = hi_(u1);
            d[4] = lo_(u2); d[5] = hi_(u2);
            d[6] = lo_(u3); d[7] = hi_(u3);
        } else {
            const float4* ar = (const float4*)((const float*)A + (size_t)gnode * KIN + k0 + koff);
            float4 v0 = ar[0], v1 = ar[1];
            float4* d = (float4*)(As + snode * AST + koff);
            d[0] = v0;
            d[1] = v1;
        }
        __syncthreads();
#pragma unroll 8
        for (int k = 0; k < BK; ++k) {
            float w[CPT];
            const float* wr = Ws + k * KOUT + jc * CPT;
            if constexpr (CPT >= 4) {
#pragma unroll
                for (int c = 0; c < CPT; c += 4) {
                    float4 wv = *(const float4*)(wr + c);
                    w[c] = wv.x; w[c + 1] = wv.y; w[c + 2] = wv.z; w[c + 3] = wv.w;
                }
            } else {
                float2 wv = *(const float2*)wr;
                w[0] = wv.x; w[1] = wv.y;
            }
            float a0 = As[(ng * 4 + 0) * AST + k];
            float a1 = As[(ng * 4 + 1) * AST + k];
            float a2 = As[(ng * 4 + 2) * AST + k];
            float a3 = As[(ng * 4 + 3) * AST + k];
#pragma unroll
            for (int c = 0; c < CPT; ++c) {
                acc[0][c] += a0 * w[c];
                acc[1][c] += a1 * w[c];
                acc[2][c] += a2 * w[c];
                acc[3][c] += a3 * w[c];
            }
        }
        __syncthreads();
    }
#pragma unroll
    for (int i = 0; i < 4; ++i) {
        int node = base + ng * 4 + i;
        if (node < n) {
            float sc = SCALE ? dis[node] : 1.0f;
            unsigned* cr = C + (size_t)node * (KOUT / 2) + jc * (CPT / 2);
#pragma unroll
            for (int c = 0; c < CPT; c += 2)
                cr[c / 2] = pack2(acc[i][c] * sc, acc[i][c + 1] * sc);
        }
    }
}

// ---------------- GCN agg over pre-scaled t' (t*dis), bf16 gather -> fp32 out -----------
template <bool RELU>
__global__ void k_agg128(const unsigned* __restrict__ t, const int* __restrict__ rptr,
                         const int* __restrict__ csr_src, const float* __restrict__ dis,
                         const float* __restrict__ bias, float* __restrict__ out, int n) {
    int wave = (blockIdx.x * blockDim.x + threadIdx.x) >> 6;
    int lane = threadIdx.x & 63;
    if (wave >= n) return;
    int dst = wave;
    float dd = dis[dst];
    float ax, ay;
    {
        unsigned u = t[(size_t)dst * 64 + lane];
        ax = lo_(u);
        ay = hi_(u);
    }
    int s = __builtin_amdgcn_readfirstlane(max(0, min(rptr[dst], EE)));
    int e = __builtin_amdgcn_readfirstlane(max(s, min(rptr[dst + 1], EE)));
    int j = s;
    for (; j + 8 <= e; j += 8) {
        int i0 = csr_src[j], i1 = csr_src[j + 1], i2 = csr_src[j + 2], i3 = csr_src[j + 3];
        int i4 = csr_src[j + 4], i5 = csr_src[j + 5], i6 = csr_src[j + 6], i7 = csr_src[j + 7];
        unsigned u0 = t[(size_t)i0 * 64 + lane], u1 = t[(size_t)i1 * 64 + lane];
        unsigned u2 = t[(size_t)i2 * 64 + lane], u3 = t[(size_t)i3 * 64 + lane];
        unsigned u4 = t[(size_t)i4 * 64 + lane], u5 = t[(size_t)i5 * 64 + lane];
        unsigned u6 = t[(size_t)i6 * 64 + lane], u7 = t[(size_t)i7 * 64 + lane];
        ax += (lo_(u0) + lo_(u1)) + (lo_(u2) + lo_(u3)) + (lo_(u4) + lo_(u5)) + (lo_(u6) + lo_(u7));
        ay += (hi_(u0) + hi_(u1)) + (hi_(u2) + hi_(u3)) + (hi_(u4) + hi_(u5)) + (hi_(u6) + hi_(u7));
    }
    for (; j + 4 <= e; j += 4) {
        int i0 = csr_src[j], i1 = csr_src[j + 1], i2 = csr_src[j + 2], i3 = csr_src[j + 3];
        unsigned u0 = t[(size_t)i0 * 64 + lane], u1 = t[(size_t)i1 * 64 + lane];
        unsigned u2 = t[(size_t)i2 * 64 + lane], u3 = t[(size_t)i3 * 64 + lane];
        ax += (lo_(u0) + lo_(u1)) + (lo_(u2) + lo_(u3));
        ay += (hi_(u0) + hi_(u1)) + (hi_(u2) + hi_(u3));
    }
    for (; j < e; ++j) {
        unsigned u0 = t[(size_t)csr_src[j] * 64 + lane];
        ax += lo_(u0);
        ay += hi_(u0);
    }
    float2 bv = *(const float2*)(bias + 2 * lane);
    float vx = ax * dd + bv.x;
    float vy = ay * dd + bv.y;
    if (RELU) { vx = fmaxf(vx, 0.f); vy = fmaxf(vy, 0.f); }
    *(float2*)(out + (size_t)dst * 128 + 2 * lane) = make_float2(vx, vy);
}

// F=64: half-wave per edge, explicit 4-batches
template <bool RELU>
__global__ void k_agg64(const unsigned* __restrict__ t, const int* __restrict__ rptr,
                        const int* __restrict__ csr_src, const float* __restrict__ dis,
                        const float* __restrict__ bias, float* __restrict__ out, int n) {
    int wave = (blockIdx.x * blockDim.x + threadIdx.x) >> 6;
    int lane = threadIdx.x & 63;
    if (wave >= n) return;
    int dst = wave;
    int half = lane >> 5, l32 = lane & 31;
    float dd = dis[dst];
    float ax = 0.f, ay = 0.f;
    if (!half) {
        unsigned u = t[(size_t)dst * 32 + l32];
        ax = lo_(u);
        ay = hi_(u);
    }
    int s = max(0, min(rptr[dst], EE));
    int e = max(s, min(rptr[dst + 1], EE));
    int cnt = e - s;
    int pairs = cnt >> 1;
    int p = 0;
    for (; p + 4 <= pairs; p += 4) {
        int jb = s + 2 * p + half;
        int i0 = csr_src[jb], i1 = csr_src[jb + 2], i2 = csr_src[jb + 4], i3 = csr_src[jb + 6];
        unsigned u0 = t[(size_t)i0 * 32 + l32], u1 = t[(size_t)i1 * 32 + l32];
        unsigned u2 = t[(size_t)i2 * 32 + l32], u3 = t[(size_t)i3 * 32 + l32];
        ax += (lo_(u0) + lo_(u1)) + (lo_(u2) + lo_(u3));
        ay += (hi_(u0) + hi_(u1)) + (hi_(u2) + hi_(u3));
    }
    for (; p < pairs; ++p) {
        int i0 = csr_src[s + 2 * p + half];
        unsigned u0 = t[(size_t)i0 * 32 + l32];
        ax += lo_(u0);
        ay += hi_(u0);
    }
    if ((cnt & 1) && !half) {
        unsigned u0 = t[(size_t)csr_src[e - 1] * 32 + l32];
        ax += lo_(u0);
        ay += hi_(u0);
    }
    ax += __shfl_down(ax, 32);
    ay += __shfl_down(ay, 32);
    if (!half) {
        float2 bv = *(const float2*)(bias + 2 * l32);
        float vx = ax * dd + bv.x;
        float vy = ay * dd + bv.y;
        if (RELU) { vx = fmaxf(vx, 0.f); vy = fmaxf(vy, 0.f); }
        *(float2*)(out + (size_t)dst * 64 + 2 * l32) = make_float2(vx, vy);
    }
}

// F=32: quarter-wave per edge, explicit 4-batches
template <bool RELU>
__global__ void k_agg32(const unsigned* __restrict__ t, const int* __restrict__ rptr,
                        const int* __restrict__ csr_src, const float* __restrict__ dis,
                        const float* __restrict__ bias, float* __restrict__ out, int n) {
    int wave = (blockIdx.x * blockDim.x + threadIdx.x) >> 6;
    int lane = threadIdx.x & 63;
    if (wave >= n) return;
    int dst = wave;
    int q = lane >> 4, l16 = lane & 15;
    float dd = dis[dst];
    float ax = 0.f, ay = 0.f;
    if (q == 0) {
        unsigned u = t[(size_t)dst * 16 + l16];
        ax = lo_(u);
        ay = hi_(u);
    }
    int s = max(0, min(rptr[dst], EE));
    int e = max(s, min(rptr[dst + 1], EE));
    int cnt = e - s;
    int quads = cnt >> 2;
    int p = 0;
    for (; p + 4 <= quads; p += 4) {
        int jb = s + 4 * p + q;
        int i0 = csr_src[jb], i1 = csr_src[jb + 4], i2 = csr_src[jb + 8], i3 = csr_src[jb + 12];
        unsigned u0 = t[(size_t)i0 * 16 + l16], u1 = t[(size_t)i1 * 16 + l16];
        unsigned u2 = t[(size_t)i2 * 16 + l16], u3 = t[(size_t)i3 * 16 + l16];
        ax += (lo_(u0) + lo_(u1)) + (lo_(u2) + lo_(u3));
        ay += (hi_(u0) + hi_(u1)) + (hi_(u2) + hi_(u3));
    }
    for (; p < quads; ++p) {
        int i0 = csr_src[s + 4 * p + q];
        unsigned u0 = t[(size_t)i0 * 16 + l16];
        ax += lo_(u0);
        ay += hi_(u0);
    }
    int rem = cnt - 4 * quads;
    if (q < rem) {
        unsigned u0 = t[(size_t)csr_src[s + 4 * quads + q] * 16 + l16];
        ax += lo_(u0);
        ay += hi_(u0);
    }
    ax += __shfl_down(ax, 32);
    ay += __shfl_down(ay, 32);
    ax += __shfl_down(ax, 16);
    ay += __shfl_down(ay, 16);
    if (q == 0) {
        float2 bv = *(const float2*)(bias + 2 * l16);
        float vx = ax * dd + bv.x;
        float vy = ay * dd + bv.y;
        if (RELU) { vx = fmaxf(vx, 0.f); vy = fmaxf(vy, 0.f); }
        *(float2*)(out + (size_t)dst * 32 + 2 * l16) = make_float2(vx, vy);
    }
}

// ---------------- GAT ----------------
__global__ void k_gat_vec(const unsigned* __restrict__ g, const float* __restrict__ a_src,
                          const float* __restrict__ a_dst, float* __restrict__ asrc,
                          float* __restrict__ adst, int n) {
    int i = blockIdx.x * 256 + threadIdx.x;
    if (i >= n) return;
    float s = 0.0f, d = 0.0f;
    const unsigned* gr = g + (size_t)i * 16;
#pragma unroll
    for (int k = 0; k < 16; ++k) {
        unsigned u = gr[k];
        float v0 = lo_(u), v1 = hi_(u);
        s += v0 * a_src[2 * k] + v1 * a_src[2 * k + 1];
        d += v0 * a_dst[2 * k] + v1 * a_dst[2 * k + 1];
    }
    asrc[i] = s;
    adst[i] = d;
}

__global__ void k_gat_agg(const unsigned* __restrict__ g, const int* __restrict__ rptr,
                          const int* __restrict__ csr_src, const float* __restrict__ asrc,
                          const float* __restrict__ adst, const float* __restrict__ gat_b,
                          float* __restrict__ out, int n) {
    int wave = (blockIdx.x * blockDim.x + threadIdx.x) >> 6;
    int lane = threadIdx.x & 63;
    if (wave >= n) return;
    int dst = wave;
    int q = lane >> 4, l16 = lane & 15;
    float ad = adst[dst];
    int s = max(0, min(rptr[dst], EE));
    int e = max(s, min(rptr[dst + 1], EE));
    float ax = 0.f, ay = 0.f, denom = 0.f;
    if (q == 0) {
        float w0 = __expf(fminf(leakyf_(asrc[dst] + ad), 80.f));
        unsigned u = g[(size_t)dst * 16 + l16];
        ax = lo_(u) * w0;
        ay = hi_(u) * w0;
        denom = w0;
    }
    int cnt = e - s;
    int quads = cnt >> 2;
    int p = 0;
    for (; p + 4 <= quads; p += 4) {
        int jb = s + 4 * p + q;
        int i0 = csr_src[jb], i1 = csr_src[jb + 4], i2 = csr_src[jb + 8], i3 = csr_src[jb + 12];
        float a0 = asrc[i0], a1 = asrc[i1], a2 = asrc[i2], a3 = asrc[i3];
        unsigned u0 = g[(size_t)i0 * 16 + l16], u1 = g[(size_t)i1 * 16 + l16];
        unsigned u2 = g[(size_t)i2 * 16 + l16], u3 = g[(size_t)i3 * 16 + l16];
        float w0 = __expf(fminf(leakyf_(a0 + ad), 80.f));
        float w1 = __expf(fminf(leakyf_(a1 + ad), 80.f));
        float w2 = __expf(fminf(leakyf_(a2 + ad), 80.f));
        float w3 = __expf(fminf(leakyf_(a3 + ad), 80.f));
        denom += (w0 + w1) + (w2 + w3);
        ax += lo_(u0) * w0 + lo_(u1) * w1 + lo_(u2) * w2 + lo_(u3) * w3;
        ay += hi_(u0) * w0 + hi_(u1) * w1 + hi_(u2) * w2 + hi_(u3) * w3;
    }
    for (; p < quads; ++p) {
        int i0 = csr_src[s + 4 * p + q];
        float wgt = __expf(fminf(leakyf_(asrc[i0] + ad), 80.f));
        unsigned u0 = g[(size_t)i0 * 16 + l16];
        denom += wgt;
        ax += lo_(u0) * wgt;
        ay += hi_(u0) * wgt;
    }
    int rem = cnt - 4 * quads;
    if (q < rem) {
        int i0 = csr_src[s + 4 * quads + q];
        float wgt = __expf(fminf(leakyf_(asrc[i0] + ad), 80.f));
        unsigned u0 = g[(size_t)i0 * 16 + l16];
        denom += wgt;
        ax += lo_(u0) * wgt;
        ay += hi_(u0) * wgt;
    }
    ax += __shfl_down(ax, 32);
    ay += __shfl_down(ay, 32);
    denom += __shfl_down(denom, 32);
    ax += __shfl_down(ax, 16);
    ay += __shfl_down(ay, 16);
    denom += __shfl_down(denom, 16);
    if (q == 0) {
        float r = rcp_(denom);
        float vx = fmaxf(ax * r + gat_b[2 * l16], 0.f);
        float vy = fmaxf(ay * r + gat_b[2 * l16 + 1], 0.f);
        *(float2*)(out + (size_t)dst * 32 + 2 * l16) = make_float2(vx, vy);
    }
}

// ---------------- fused LSTM + BN + FC: GEMV-style, one thread per (node, dir, j-half) ----
// 256 threads = 64 nodes/block x 4 parts. part = (dir<<1)|jhalf is wave-uniform, so ALL
// weight/bias/gamma/beta/fcW accesses are wave-uniform -> scalar (s_load) path, no LDS
// staging of weights, no per-thread weight arrays. The r vector is never materialized:
// FC partials accumulate on the fly; only a 10 KB ps buffer combines the 4 parts.
__global__ __launch_bounds__(256) void k_lstm_fc(const float* __restrict__ h,
                                                 const float* __restrict__ wp,
                                                 void* __restrict__ out,
                                                 const int* __restrict__ flags, int n) {
    __shared__ float ps[4 * 640];
    int t = threadIdx.x;
    int nd = t & 63;
    int part = __builtin_amdgcn_readfirstlane(t >> 6);  // wave-uniform: 0..3
    int dir = part >> 1, jh = part & 1;
    int base = blockIdx.x * 64;
    int node = min(base + nd, n - 1);

    // this thread's h row (32 floats) in VGPRs
    float hv[32];
    {
        const float4* hr = (const float4*)(h + (size_t)node * 32);
#pragma unroll
        for (int qq = 0; qq < 8; ++qq) {
            float4 v = hr[qq];
            hv[4 * qq + 0] = v.x;
            hv[4 * qq + 1] = v.y;
            hv[4 * qq + 2] = v.z;
            hv[4 * qq + 3] = v.w;
        }
    }

    const float* W = wp + (dir ? OFF_WIHB : OFF_WIHF);
    const float* bi = wp + (dir ? OFF_BIHB : OFF_BIHF);
    const float* bh = wp + (dir ? OFF_BHHB : OFF_BHHF);
    const float* fcw = wp + OFF_FCW;
    float p10[10];
#pragma unroll
    for (int c = 0; c < 10; ++c) p10[c] = 0.f;

    int j0 = jh * 32;
#pragma unroll 2
    for (int j = j0; j < j0 + 32; ++j) {
        const float* wi = W + (size_t)j * 32;          // gate i
        const float* wc = W + (size_t)(128 + j) * 32;  // gate g(c)
        const float* wo = W + (size_t)(192 + j) * 32;  // gate o
        float ai = bi[j] + bh[j];
        float ac = bi[128 + j] + bh[128 + j];
        float ao = bi[192 + j] + bh[192 + j];
#pragma unroll
        for (int k = 0; k < 32; ++k) {
            float hk = hv[k];
            ai += hk * wi[k];
            ac += hk * wc[k];
            ao += hk * wo[k];
        }
        float v = sigmoidf_(ao) * tanhf_(sigmoidf_(ai) * tanhf_(ac));
        int jj = dir * 64 + j;
        float r = v * (wp[OFF_GAMMA + jj] * rsqrtf(1.0f + 1e-5f)) + wp[OFF_BETA + jj];
#pragma unroll
        for (int c = 0; c < 10; ++c) p10[c] += r * fcw[c * 128 + jj];
    }
#pragma unroll
    for (int c = 0; c < 10; ++c) ps[part * 640 + nd * 10 + c] = p10[c];
    __syncthreads();
    bool f32o = flags[0] != 0;
    for (int idx = t; idx < 640; idx += 256) {
        int gnode = base + idx / 10;
        if (gnode < n) {
            int c = idx % 10;
            float v = wp[OFF_FCB + c] + ps[idx] + ps[640 + idx] + ps[1280 + idx] + ps[1920 + idx];
            if (f32o) ((float*)out)[(size_t)base * 10 + idx] = v;
            else ((unsigned short*)out)[(size_t)base * 10 + idx] = f2bf(v);
        }
    }
}

// ---------------- launch ----------------
extern "C" void kernel_launch(void* const* d_in, const int* in_sizes, int n_in,
                              void* d_out, int out_size, void* d_ws, size_t ws_size,
                              hipStream_t stream) {
    const int N = NN;

    char* w = (char*)d_ws;
    auto alloc = [&](size_t bytes) {
        void* p = (void*)w;
        w += (bytes + 255) & ~(size_t)255;
        return p;
    };
    int* flags = (int*)alloc(256);
    float* wpool = (float*)alloc((size_t)WTOTAL * 4);
    float* dis = (float*)alloc((size_t)N * 4);
    int* rptr = (int*)alloc((size_t)(N + 1) * 4);
    int* csr_src = (int*)alloc((size_t)EE * 4);
    unsigned* gh = (unsigned*)alloc((size_t)NBK * 256 * 4);
    unsigned* gh2 = (unsigned*)alloc((size_t)NBK * 256 * 4);
    int* bb = (int*)alloc(1024);
    int2* ebkt = (int2*)alloc((size_t)EE * 8);
    float* asrc = (float*)alloc((size_t)N * 4);
    float* adst = (float*)alloc((size_t)N * 4);
    unsigned* bufT = (unsigned*)alloc((size_t)N * 64 * 4);  // bf16 N x 128
    float* bufH = (float*)alloc((size_t)N * 128 * 4);       // fp32 N x 128

    WSrc ws_srcs;
    for (int i = 0; i < 20; ++i) ws_srcs.p[i] = d_in[2 + i];

    const int NB = (N + 255) / 256;
    const int AGG = (N + 3) / 4;
    const int TMB = (N + 63) / 64;
    const int LFB = (N + 63) / 64;
    const int WB = (WTOTAL + 255) / 256;

    k_detect<<<1, 256, 0, stream>>>((const unsigned short*)d_in[0],
                                    (const unsigned int*)d_in[1], flags);
    k_cvt_w<<<WB, 256, 0, stream>>>(ws_srcs, wpool, flags, WTOTAL);
    // bucketed CSR build
    k_hist<<<NBK, 256, 0, stream>>>(d_in[1], gh, flags);
    k_bscan<<<1, 256, 0, stream>>>(gh, gh2, bb, rptr);
    k_scatter<<<NBK, 256, 0, stream>>>(d_in[1], gh2, bb, ebkt, flags);
    k_bucket_csr<<<NBK, 256, 0, stream>>>(ebkt, bb, rptr, dis, csr_src);

    // GCN 1 (x -> t1' = (x@W1)*dis, bf16) : flag-selected input dtype variant
    k_tile_mm<128, 128, 0, true><<<TMB, 256, 0, stream>>>(d_in[0], wpool + OFF_W1, bufT, N, flags, 0, dis);
    k_tile_mm<128, 128, 1, true><<<TMB, 256, 0, stream>>>(d_in[0], wpool + OFF_W1, bufT, N, flags, 1, dis);
    k_agg128<true><<<AGG, 256, 0, stream>>>(bufT, rptr, csr_src, dis, wpool + OFF_B1, bufH, N);
    // GCN 2
    k_tile_mm<128, 64, 1, true><<<TMB, 256, 0, stream>>>(bufH, wpool + OFF_W2, bufT, N, flags, -1, dis);
    k_agg64<true><<<AGG, 256, 0, stream>>>(bufT, rptr, csr_src, dis, wpool + OFF_B2, bufH, N);
    // GCN 3
    k_tile_mm<64, 32, 1, true><<<TMB, 256, 0, stream>>>(bufH, wpool + OFF_W3, bufT, N, flags, -1, dis);
    k_agg32<false><<<AGG, 256, 0, stream>>>(bufT, rptr, csr_src, dis, wpool + OFF_B3, bufH, N);
    // GAT (unscaled)
    k_tile_mm<32, 32, 1, false><<<TMB, 256, 0, stream>>>(bufH, wpool + OFF_GATW, bufT, N, flags, -1, dis);
    k_gat_vec<<<NB, 256, 0, stream>>>(bufT, wpool + OFF_GAS, wpool + OFF_GAD, asrc, adst, N);
    k_gat_agg<<<AGG, 256, 0, stream>>>(bufT, rptr, csr_src, asrc, adst, wpool + OFF_GAB, bufH, N);
    // LSTM + BN + FC (GEMV-style)
    k_lstm_fc<<<LFB, 256, 0, stream>>>(bufH, wpool, d_out, flags, N);
}

// Round 2
// 379.526 us; speedup vs baseline: 1.0090x; 1.0090x over previous
//
#include <hip/hip_runtime.h>
#include <hip/hip_bf16.h>
#include <math.h>

typedef __hip_bfloat16 bf16;

#define NN 50000
#define EE 800000
#define EPB 4096   // edges per block (hist/scatter)
#define NBK 196    // dst buckets = ceil(NN/256); also blocks for hist/scatter
#define BCAP 6144  // max edges per bucket (mean 4096, sd ~64)

__device__ __forceinline__ float b2f(bf16 v) { return __bfloat162float(v); }
__device__ __forceinline__ float rcp_(float x) { return __builtin_amdgcn_rcpf(x); }
__device__ __forceinline__ float sigmoidf_(float x) { return rcp_(1.0f + __expf(-x)); }
__device__ __forceinline__ float tanhf_(float x) {
    float xx = fminf(fmaxf(x, -15.0f), 15.0f);
    float e = __expf(2.0f * xx);
    return (e - 1.0f) * rcp_(e + 1.0f);
}
__device__ __forceinline__ float leakyf_(float x) { return x > 0.0f ? x : 0.2f * x; }
__device__ __forceinline__ unsigned short f2bf(float f) {
    unsigned u = __float_as_uint(f);
    unsigned r = (u + 0x7FFFu + ((u >> 16) & 1u)) >> 16;
    return (unsigned short)r;
}
__device__ __forceinline__ unsigned pack2(float a, float b) {
    return (unsigned)f2bf(a) | ((unsigned)f2bf(b) << 16);
}
__device__ __forceinline__ float lo_(unsigned u) { return __uint_as_float(u << 16); }
__device__ __forceinline__ float hi_(unsigned u) { return __uint_as_float(u & 0xFFFF0000u); }

// weight-pool element offsets (fp32 pool in ws)
#define OFF_W1 0
#define OFF_B1 16384
#define OFF_W2 16512
#define OFF_B2 24704
#define OFF_W3 24768
#define OFF_B3 26816
#define OFF_GATW 26848
#define OFF_GAS 27872
#define OFF_GAD 27904
#define OFF_GAB 27936
#define OFF_WIHF 27968
#define OFF_BIHF 36160
#define OFF_BHHF 36416
#define OFF_WIHB 36672
#define OFF_BIHB 44864
#define OFF_BHHB 45120
#define OFF_GAMMA 45376
#define OFF_BETA 45504
#define OFF_FCW 45632
#define OFF_FCB 46912
#define WTOTAL 46922

struct WSrc { const void* p[20]; };

// ---------------- dtype detection ----------------
__global__ void k_detect(const unsigned short* __restrict__ xraw,
                         const unsigned int* __restrict__ eraw, int* __restrict__ flags) {
    __shared__ int f32f, i64f;
    int t = threadIdx.x;
    if (t == 0) { f32f = 0; i64f = 1; }
    __syncthreads();
    for (int i = t; i < 4096; i += 256) {
        unsigned short u = xraw[i];
        int ex = (u >> 7) & 0xFF;
        if (ex >= 0xC0) atomicOr(&f32f, 1);
        if (eraw[2 * i + 1] != 0u) atomicAnd(&i64f, 0);
    }
    __syncthreads();
    if (t == 0) { flags[0] = f32f; flags[1] = i64f; }
}

// ---------------- weight conversion into fp32 pool ----------------
__global__ void k_cvt_w(WSrc srcs, float* __restrict__ dst, const int* __restrict__ flags,
                        int total) {
    constexpr int WOFF[21] = {OFF_W1,   OFF_B1,   OFF_W2,   OFF_B2,   OFF_W3,   OFF_B3,
                              OFF_GATW, OFF_GAS,  OFF_GAD,  OFF_GAB,  OFF_WIHF, OFF_BIHF,
                              OFF_BHHF, OFF_WIHB, OFF_BIHB, OFF_BHHB, OFF_GAMMA, OFF_BETA,
                              OFF_FCW,  OFF_FCB,  WTOTAL};
    int i = blockIdx.x * 256 + threadIdx.x;
    if (i >= total) return;
    int tn = 0;
#pragma unroll
    for (int j = 1; j < 20; ++j)
        if (i >= WOFF[j]) tn = j;
    int local = i - WOFF[tn];
    if (flags[0]) dst[i] = ((const float*)srcs.p[tn])[local];
    else dst[i] = b2f(((const bf16*)srcs.p[tn])[local]);
}

// ---------------- bucketed CSR build ----------------
// P1: per-edge-block histogram over dst buckets (LDS atomics only)
__global__ __launch_bounds__(256) void k_hist(const void* __restrict__ eraw,
                                              unsigned* __restrict__ gh,
                                              const int* __restrict__ flags) {
    __shared__ int h[256];
    int t = threadIdx.x, b = blockIdx.x;
    h[t] = 0;
    __syncthreads();
    int e0 = b * EPB;
    bool i64 = flags[1] != 0;
    for (int i = t; i < EPB; i += 256) {
        int e = e0 + i;
        if (e < EE) {
            int d = i64 ? (int)((const long long*)eraw)[EE + e] : ((const int*)eraw)[EE + e];
            d = min(max(d, 0), NN - 1);
            atomicAdd(&h[d >> 8], 1);
        }
    }
    __syncthreads();
    gh[b * 256 + t] = (unsigned)h[t];
}

// P2: per-(block,bucket) bases + bucket bases (one block; coalesced reads)
__global__ __launch_bounds__(256) void k_bscan(const unsigned* __restrict__ gh,
                                               unsigned* __restrict__ gh2,
                                               int* __restrict__ bb, int* __restrict__ rptr) {
    __shared__ int s[256];
    int t = threadIdx.x;
    unsigned run = 0;
    for (int blk = 0; blk < NBK; ++blk) {
        unsigned v = gh[blk * 256 + t];
        gh2[blk * 256 + t] = run;  // within-bucket offset of this edge-block
        run += v;
    }
    s[t] = (int)run;
    __syncthreads();
    for (int o = 1; o < 256; o <<= 1) {
        int x = (t >= o) ? s[t - o] : 0;
        __syncthreads();
        s[t] += x;
        __syncthreads();
    }
    bb[t] = s[t] - (int)run;  // exclusive: bucket base (bb[196] lands on EE)
    if (t == 0) rptr[NN] = EE;
}

// P3: scatter (src,dst) pairs into bucket-partitioned array (LDS cursors, window writes)
__global__ __launch_bounds__(256) void k_scatter(const void* __restrict__ eraw,
                                                 const unsigned* __restrict__ gh2,
                                                 const int* __restrict__ bb,
                                                 int2* __restrict__ ebkt,
                                                 const int* __restrict__ flags) {
    __shared__ unsigned cur[256];
    int t = threadIdx.x, b = blockIdx.x;
    cur[t] = gh2[b * 256 + t] + (unsigned)bb[t];
    __syncthreads();
    int e0 = b * EPB;
    bool i64 = flags[1] != 0;
    for (int i = t; i < EPB; i += 256) {
        int e = e0 + i;
        if (e < EE) {
            int sn, d;
            if (i64) {
                sn = (int)((const long long*)eraw)[e];
                d = (int)((const long long*)eraw)[EE + e];
            } else {
                sn = ((const int*)eraw)[e];
                d = ((const int*)eraw)[EE + e];
            }
            sn = min(max(sn, 0), NN - 1);
            d = min(max(d, 0), NN - 1);
            unsigned pos = atomicAdd(&cur[d >> 8], 1u);
            if (pos < (unsigned)EE) ebkt[pos] = make_int2(sn, d);
        }
    }
}

// P4: per-bucket LDS counting sort -> coalesced csr_src segment + rptr/dis
__global__ __launch_bounds__(256) void k_bucket_csr(const int2* __restrict__ ebkt,
                                                    const int* __restrict__ bb,
                                                    int* __restrict__ rptr,
                                                    float* __restrict__ dis,
                                                    int* __restrict__ csr_src) {
    __shared__ int hist[256];
    __shared__ int excl[256];
    __shared__ int cur[256];
    __shared__ int sorted[BCAP];
    int t = threadIdx.x, b = blockIdx.x;
    int s0 = bb[b], s1 = bb[b + 1];
    int len = min(s1 - s0, BCAP);
    hist[t] = 0;
    __syncthreads();
    for (int i = t; i < len; i += 256) atomicAdd(&hist[ebkt[s0 + i].y & 255], 1);
    __syncthreads();
    int v = hist[t];
    excl[t] = v;
    __syncthreads();
    for (int o = 1; o < 256; o <<= 1) {
        int x = (t >= o) ? excl[t - o] : 0;
        __syncthreads();
        excl[t] += x;
        __syncthreads();
    }
    int loc = excl[t] - v;  // local exclusive offset
    int node = b * 256 + t;
    if (node < NN) {
        rptr[node] = s0 + loc;
        dis[node] = rsqrtf((float)(v + 1));
    }
    cur[t] = loc;
    __syncthreads();
    for (int i = t; i < len; i += 256) {
        int2 p = ebkt[s0 + i];
        int pos = atomicAdd(&cur[p.y & 255], 1);
        if (pos < BCAP) sorted[pos] = p.x;
    }
    __syncthreads();
    for (int i = t; i < len; i += 256) csr_src[s0 + i] = sorted[i];
}

// ---------------- LDS-tiled GEMM: C(bf16) = A @ W, optional per-node dis scaling --------
template <int KIN, int KOUT, int MODE, bool SCALE>
__global__ __launch_bounds__(256) void k_tile_mm(const void* __restrict__ A,
                                                 const float* __restrict__ W,
                                                 unsigned* __restrict__ C, int n,
                                                 const int* __restrict__ flags, int want,
                                                 const float* __restrict__ dis) {
    if (want >= 0 && flags[0] != want) return;
    constexpr int BK = 32;
    constexpr int AST = BK + 4;
    constexpr int CPT = KOUT / 16;  // 8 / 4 / 2
    __shared__ float As[64 * AST];
    __shared__ float Ws[BK * KOUT];
    int t = threadIdx.x;
    int jc = t & 15;
    int ng = t >> 4;
    int base = blockIdx.x * 64;
    float acc[4][CPT];
#pragma unroll
    for (int i = 0; i < 4; ++i)
#pragma unroll
        for (int c = 0; c < CPT; ++c) acc[i][c] = 0.f;
    int snode = t >> 2;
    int gnode = min(base + snode, n - 1);
    int koff = (t & 3) * 8;
    for (int k0 = 0; k0 < KIN; k0 += BK) {
        {
            const float4* src = (const float4*)(W + k0 * KOUT);
            float4* dst = (float4*)Ws;
#pragma unroll
            for (int p = 0; p < BK * KOUT / 1024; ++p) dst[t + p * 256] = src[t + p * 256];
        }
        if (MODE == 0) {
            const unsigned* xr = (const unsigned*)A + (size_t)gnode * (KIN / 2) + (k0 + koff) / 2;
            unsigned u0 = xr[0], u1 = xr[1], u2 = xr[2], u3 = xr[3];
            float* d = As + snode * AST + koff;
            d[0] = lo_(u0); d[1] = hi_(u0);
            d[2] = lo_(u1); d[3] = hi_(u1);
            d[4] = lo_(u2); d[5] = hi_(u2);
            d[6] = lo_(u3); d[7] = hi_(u3);
        } else {
            const float4* ar = (const float4*)((const float*)A + (size_t)gnode * KIN + k0 + koff);
            float4 v0 = ar[0], v1 = ar[1];
            float4* d = (float4*)(As + snode * AST + koff);
            d[0] = v0;
            d[1] = v1;
        }
        __syncthreads();
#pragma unroll 8
        for (int k = 0; k < BK; ++k) {
            float w[CPT];
            const float* wr = Ws + k * KOUT + jc * CPT;
            if constexpr (CPT >= 4) {
#pragma unroll
                for (int c = 0; c < CPT; c += 4) {
                    float4 wv = *(const float4*)(wr + c);
                    w[c] = wv.x; w[c + 1] = wv.y; w[c + 2] = wv.z; w[c + 3] = wv.w;
                }
            } else {
                float2 wv = *(const float2*)wr;
                w[0] = wv.x; w[1] = wv.y;
            }
            float a0 = As[(ng * 4 + 0) * AST + k];
            float a1 = As[(ng * 4 + 1) * AST + k];
            float a2 = As[(ng * 4 + 2) * AST + k];
            float a3 = As[(ng * 4 + 3) * AST + k];
#pragma unroll
            for (int c = 0; c < CPT; ++c) {
                acc[0][c] += a0 * w[c];
                acc[1][c] += a1 * w[c];
                acc[2][c] += a2 * w[c];
                acc[3][c] += a3 * w[c];
            }
        }
        __syncthreads();
    }
#pragma unroll
    for (int i = 0; i < 4; ++i) {
        int node = base + ng * 4 + i;
        if (node < n) {
            float sc = SCALE ? dis[node] : 1.0f;
            unsigned* cr = C + (size_t)node * (KOUT / 2) + jc * (CPT / 2);
#pragma unroll
            for (int c = 0; c < CPT; c += 2)
                cr[c / 2] = pack2(acc[i][c] * sc, acc[i][c + 1] * sc);
        }
    }
}

// ---------------- GCN agg over pre-scaled t' (t*dis), bf16 gather -> fp32 out -----------
template <bool RELU>
__global__ void k_agg128(const unsigned* __restrict__ t, const int* __restrict__ rptr,
                         const int* __restrict__ csr_src, const float* __restrict__ dis,
                         const float* __restrict__ bias, float* __restrict__ out, int n) {
    int wave = (blockIdx.x * blockDim.x + threadIdx.x) >> 6;
    int lane = threadIdx.x & 63;
    if (wave >= n) return;
    int dst = wave;
    float dd = dis[dst];
    float ax, ay;
    {
        unsigned u = t[(size_t)dst * 64 + lane];
        ax = lo_(u);
        ay = hi_(u);
    }
    int s = __builtin_amdgcn_readfirstlane(max(0, min(rptr[dst], EE)));
    int e = __builtin_amdgcn_readfirstlane(max(s, min(rptr[dst + 1], EE)));
    int j = s;
    for (; j + 8 <= e; j += 8) {
        int i0 = csr_src[j], i1 = csr_src[j + 1], i2 = csr_src[j + 2], i3 = csr_src[j + 3];
        int i4 = csr_src[j + 4], i5 = csr_src[j + 5], i6 = csr_src[j + 6], i7 = csr_src[j + 7];
        unsigned u0 = t[(size_t)i0 * 64 + lane], u1 = t[(size_t)i1 * 64 + lane];
        unsigned u2 = t[(size_t)i2 * 64 + lane], u3 = t[(size_t)i3 * 64 + lane];
        unsigned u4 = t[(size_t)i4 * 64 + lane], u5 = t[(size_t)i5 * 64 + lane];
        unsigned u6 = t[(size_t)i6 * 64 + lane], u7 = t[(size_t)i7 * 64 + lane];
        ax += (lo_(u0) + lo_(u1)) + (lo_(u2) + lo_(u3)) + (lo_(u4) + lo_(u5)) + (lo_(u6) + lo_(u7));
        ay += (hi_(u0) + hi_(u1)) + (hi_(u2) + hi_(u3)) + (hi_(u4) + hi_(u5)) + (hi_(u6) + hi_(u7));
    }
    for (; j + 4 <= e; j += 4) {
        int i0 = csr_src[j], i1 = csr_src[j + 1], i2 = csr_src[j + 2], i3 = csr_src[j + 3];
        unsigned u0 = t[(size_t)i0 * 64 + lane], u1 = t[(size_t)i1 * 64 + lane];
        unsigned u2 = t[(size_t)i2 * 64 + lane], u3 = t[(size_t)i3 * 64 + lane];
        ax += (lo_(u0) + lo_(u1)) + (lo_(u2) + lo_(u3));
        ay += (hi_(u0) + hi_(u1)) + (hi_(u2) + hi_(u3));
    }
    for (; j < e; ++j) {
        unsigned u0 = t[(size_t)csr_src[j] * 64 + lane];
        ax += lo_(u0);
        ay += hi_(u0);
    }
    float2 bv = *(const float2*)(bias + 2 * lane);
    float vx = ax * dd + bv.x;
    float vy = ay * dd + bv.y;
    if (RELU) { vx = fmaxf(vx, 0.f); vy = fmaxf(vy, 0.f); }
    *(float2*)(out + (size_t)dst * 128 + 2 * lane) = make_float2(vx, vy);
}

// F=64: half-wave per edge, explicit 4-batches
template <bool RELU>
__global__ void k_agg64(const unsigned* __restrict__ t, const int* __restrict__ rptr,
                        const int* __restrict__ csr_src, const float* __restrict__ dis,
                        const float* __restrict__ bias, float* __restrict__ out, int n) {
    int wave = (blockIdx.x * blockDim.x + threadIdx.x) >> 6;
    int lane = threadIdx.x & 63;
    if (wave >= n) return;
    int dst = wave;
    int half = lane >> 5, l32 = lane & 31;
    float dd = dis[dst];
    float ax = 0.f, ay = 0.f;
    if (!half) {
        unsigned u = t[(size_t)dst * 32 + l32];
        ax = lo_(u);
        ay = hi_(u);
    }
    int s = max(0, min(rptr[dst], EE));
    int e = max(s, min(rptr[dst + 1], EE));
    int cnt = e - s;
    int pairs = cnt >> 1;
    int p = 0;
    for (; p + 4 <= pairs; p += 4) {
        int jb = s + 2 * p + half;
        int i0 = csr_src[jb], i1 = csr_src[jb + 2], i2 = csr_src[jb + 4], i3 = csr_src[jb + 6];
        unsigned u0 = t[(size_t)i0 * 32 + l32], u1 = t[(size_t)i1 * 32 + l32];
        unsigned u2 = t[(size_t)i2 * 32 + l32], u3 = t[(size_t)i3 * 32 + l32];
        ax += (lo_(u0) + lo_(u1)) + (lo_(u2) + lo_(u3));
        ay += (hi_(u0) + hi_(u1)) + (hi_(u2) + hi_(u3));
    }
    for (; p < pairs; ++p) {
        int i0 = csr_src[s + 2 * p + half];
        unsigned u0 = t[(size_t)i0 * 32 + l32];
        ax += lo_(u0);
        ay += hi_(u0);
    }
    if ((cnt & 1) && !half) {
        unsigned u0 = t[(size_t)csr_src[e - 1] * 32 + l32];
        ax += lo_(u0);
        ay += hi_(u0);
    }
    ax += __shfl_down(ax, 32);
    ay += __shfl_down(ay, 32);
    if (!half) {
        float2 bv = *(const float2*)(bias + 2 * l32);
        float vx = ax * dd + bv.x;
        float vy = ay * dd + bv.y;
        if (RELU) { vx = fmaxf(vx, 0.f); vy = fmaxf(vy, 0.f); }
        *(float2*)(out + (size_t)dst * 64 + 2 * l32) = make_float2(vx, vy);
    }
}

// F=32: quarter-wave per edge, explicit 4-batches
template <bool RELU>
__global__ void k_agg32(const unsigned* __restrict__ t, const int* __restrict__ rptr,
                        const int* __restrict__ csr_src, const float* __restrict__ dis,
                        const float* __restrict__ bias, float* __restrict__ out, int n) {
    int wave = (blockIdx.x * blockDim.x + threadIdx.x) >> 6;
    int lane = threadIdx.x & 63;
    if (wave >= n) return;
    int dst = wave;
    int q = lane >> 4, l16 = lane & 15;
    float dd = dis[dst];
    float ax = 0.f, ay = 0.f;
    if (q == 0) {
        unsigned u = t[(size_t)dst * 16 + l16];
        ax = lo_(u);
        ay = hi_(u);
    }
    int s = max(0, min(rptr[dst], EE));
    int e = max(s, min(rptr[dst + 1], EE));
    int cnt = e - s;
    int quads = cnt >> 2;
    int p = 0;
    for (; p + 4 <= quads; p += 4) {
        int jb = s + 4 * p + q;
        int i0 = csr_src[jb], i1 = csr_src[jb + 4], i2 = csr_src[jb + 8], i3 = csr_src[jb + 12];
        unsigned u0 = t[(size_t)i0 * 16 + l16], u1 = t[(size_t)i1 * 16 + l16];
        unsigned u2 = t[(size_t)i2 * 16 + l16], u3 = t[(size_t)i3 * 16 + l16];
        ax += (lo_(u0) + lo_(u1)) + (lo_(u2) + lo_(u3));
        ay += (hi_(u0) + hi_(u1)) + (hi_(u2) + hi_(u3));
    }
    for (; p < quads; ++p) {
        int i0 = csr_src[s + 4 * p + q];
        unsigned u0 = t[(size_t)i0 * 16 + l16];
        ax += lo_(u0);
        ay += hi_(u0);
    }
    int rem = cnt - 4 * quads;
    if (q < rem) {
        unsigned u0 = t[(size_t)csr_src[s + 4 * quads + q] * 16 + l16];
        ax += lo_(u0);
        ay += hi_(u0);
    }
    ax += __shfl_down(ax, 32);
    ay += __shfl_down(ay, 32);
    ax += __shfl_down(ax, 16);
    ay += __shfl_down(ay, 16);
    if (q == 0) {
        float2 bv = *(const float2*)(bias + 2 * l16);
        float vx = ax * dd + bv.x;
        float vy = ay * dd + bv.y;
        if (RELU) { vx = fmaxf(vx, 0.f); vy = fmaxf(vy, 0.f); }
        *(float2*)(out + (size_t)dst * 32 + 2 * l16) = make_float2(vx, vy);
    }
}

// ---------------- GAT ----------------
__global__ void k_gat_vec(const unsigned* __restrict__ g, const float* __restrict__ a_src,
                          const float* __restrict__ a_dst, float* __restrict__ asrc,
                          float* __restrict__ adst, int n) {
    int i = blockIdx.x * 256 + threadIdx.x;
    if (i >= n) return;
    float s = 0.0f, d = 0.0f;
    const unsigned* gr = g + (size_t)i * 16;
#pragma unroll
    for (int k = 0; k < 16; ++k) {
        unsigned u = gr[k];
        float v0 = lo_(u), v1 = hi_(u);
        s += v0 * a_src[2 * k] + v1 * a_src[2 * k + 1];
        d += v0 * a_dst[2 * k] + v1 * a_dst[2 * k + 1];
    }
    asrc[i] = s;
    adst[i] = d;
}

__global__ void k_gat_agg(const unsigned* __restrict__ g, const int* __restrict__ rptr,
                          const int* __restrict__ csr_src, const float* __restrict__ asrc,
                          const float* __restrict__ adst, const float* __restrict__ gat_b,
                          float* __restrict__ out, int n) {
    int wave = (blockIdx.x * blockDim.x + threadIdx.x) >> 6;
    int lane = threadIdx.x & 63;
    if (wave >= n) return;
    int dst = wave;
    int q = lane >> 4, l16 = lane & 15;
    float ad = adst[dst];
    int s = max(0, min(rptr[dst], EE));
    int e = max(s, min(rptr[dst + 1], EE));
    float ax = 0.f, ay = 0.f, denom = 0.f;
    if (q == 0) {
        float w0 = __expf(fminf(leakyf_(asrc[dst] + ad), 80.f));
        unsigned u = g[(size_t)dst * 16 + l16];
        ax = lo_(u) * w0;
        ay = hi_(u) * w0;
        denom = w0;
    }
    int cnt = e - s;
    int quads = cnt >> 2;
    int p = 0;
    for (; p + 4 <= quads; p += 4) {
        int jb = s + 4 * p + q;
        int i0 = csr_src[jb], i1 = csr_src[jb + 4], i2 = csr_src[jb + 8], i3 = csr_src[jb + 12];
        float a0 = asrc[i0], a1 = asrc[i1], a2 = asrc[i2], a3 = asrc[i3];
        unsigned u0 = g[(size_t)i0 * 16 + l16], u1 = g[(size_t)i1 * 16 + l16];
        unsigned u2 = g[(size_t)i2 * 16 + l16], u3 = g[(size_t)i3 * 16 + l16];
        float w0 = __expf(fminf(leakyf_(a0 + ad), 80.f));
        float w1 = __expf(fminf(leakyf_(a1 + ad), 80.f));
        float w2 = __expf(fminf(leakyf_(a2 + ad), 80.f));
        float w3 = __expf(fminf(leakyf_(a3 + ad), 80.f));
        denom += (w0 + w1) + (w2 + w3);
        ax += lo_(u0) * w0 + lo_(u1) * w1 + lo_(u2) * w2 + lo_(u3) * w3;
        ay += hi_(u0) * w0 + hi_(u1) * w1 + hi_(u2) * w2 + hi_(u3) * w3;
    }
    for (; p < quads; ++p) {
        int i0 = csr_src[s + 4 * p + q];
        float wgt = __expf(fminf(leakyf_(asrc[i0] + ad), 80.f));
        unsigned u0 = g[(size_t)i0 * 16 + l16];
        denom += wgt;
        ax += lo_(u0) * wgt;
        ay += hi_(u0) * wgt;
    }
    int rem = cnt - 4 * quads;
    if (q < rem) {
        int i0 = csr_src[s + 4 * quads + q];
        float wgt = __expf(fminf(leakyf_(asrc[i0] + ad), 80.f));
        unsigned u0 = g[(size_t)i0 * 16 + l16];
        denom += wgt;
        ax += lo_(u0) * wgt;
        ay += hi_(u0) * wgt;
    }
    ax += __shfl_down(ax, 32);
    ay += __shfl_down(ay, 32);
    denom += __shfl_down(denom, 32);
    ax += __shfl_down(ax, 16);
    ay += __shfl_down(ay, 16);
    denom += __shfl_down(denom, 16);
    if (q == 0) {
        float r = rcp_(denom);
        float vx = fmaxf(ax * r + gat_b[2 * l16], 0.f);
        float vy = fmaxf(ay * r + gat_b[2 * l16 + 1], 0.f);
        *(float2*)(out + (size_t)dst * 32 + 2 * l16) = make_float2(vx, vy);
    }
}

// ---------------- fused LSTM + BN + FC: GEMV-style, one thread per (node, dir, j-quarter) -
// 512 threads = 64 nodes/block x 8 parts. part = t>>6 is wave-uniform, so ALL
// weight/bias/gamma/beta/fcW accesses are wave-uniform -> scalar (s_load) path.
// 8-way j-split doubles the wave count (6256 waves, ~6.1/SIMD) vs the 4-way version,
// to hide the serial s_load(K$ ~200cy) -> 96 FMA dependency chain. The r vector is never
// materialized: FC partials accumulate on the fly; a 20 KB ps buffer combines the 8 parts.
__global__ __launch_bounds__(512) void k_lstm_fc(const float* __restrict__ h,
                                                 const float* __restrict__ wp,
                                                 void* __restrict__ out,
                                                 const int* __restrict__ flags, int n) {
    __shared__ float ps[8 * 640];
    int t = threadIdx.x;
    int nd = t & 63;
    int part = __builtin_amdgcn_readfirstlane(t >> 6);  // wave-uniform: 0..7
    int dir = part >> 2, jq = part & 3;
    int base = blockIdx.x * 64;
    int node = min(base + nd, n - 1);

    // this thread's h row (32 floats) in VGPRs
    float hv[32];
    {
        const float4* hr = (const float4*)(h + (size_t)node * 32);
#pragma unroll
        for (int qq = 0; qq < 8; ++qq) {
            float4 v = hr[qq];
            hv[4 * qq + 0] = v.x;
            hv[4 * qq + 1] = v.y;
            hv[4 * qq + 2] = v.z;
            hv[4 * qq + 3] = v.w;
        }
    }

    const float* W = wp + (dir ? OFF_WIHB : OFF_WIHF);
    const float* bi = wp + (dir ? OFF_BIHB : OFF_BIHF);
    const float* bh = wp + (dir ? OFF_BHHB : OFF_BHHF);
    const float* fcw = wp + OFF_FCW;
    float p10[10];
#pragma unroll
    for (int c = 0; c < 10; ++c) p10[c] = 0.f;

    int j0 = jq * 16;
#pragma unroll 2
    for (int j = j0; j < j0 + 16; ++j) {
        const float* wi = W + (size_t)j * 32;          // gate i
        const float* wc = W + (size_t)(128 + j) * 32;  // gate g(c)
        const float* wo = W + (size_t)(192 + j) * 32;  // gate o
        float ai = bi[j] + bh[j];
        float ac = bi[128 + j] + bh[128 + j];
        float ao = bi[192 + j] + bh[192 + j];
#pragma unroll
        for (int k = 0; k < 32; ++k) {
            float hk = hv[k];
            ai += hk * wi[k];
            ac += hk * wc[k];
            ao += hk * wo[k];
        }
        float v = sigmoidf_(ao) * tanhf_(sigmoidf_(ai) * tanhf_(ac));
        int jj = dir * 64 + j;
        float r = v * (wp[OFF_GAMMA + jj] * rsqrtf(1.0f + 1e-5f)) + wp[OFF_BETA + jj];
#pragma unroll
        for (int c = 0; c < 10; ++c) p10[c] += r * fcw[c * 128 + jj];
    }
#pragma unroll
    for (int c = 0; c < 10; ++c) ps[part * 640 + nd * 10 + c] = p10[c];
    __syncthreads();
    bool f32o = flags[0] != 0;
    for (int idx = t; idx < 640; idx += 512) {
        int gnode = base + idx / 10;
        if (gnode < n) {
            int c = idx % 10;
            float v = wp[OFF_FCB + c];
#pragma unroll
            for (int p = 0; p < 8; ++p) v += ps[p * 640 + idx];
            if (f32o) ((float*)out)[(size_t)base * 10 + idx] = v;
            else ((unsigned short*)out)[(size_t)base * 10 + idx] = f2bf(v);
        }
    }
}

// ---------------- launch ----------------
extern "C" void kernel_launch(void* const* d_in, const int* in_sizes, int n_in,
                              void* d_out, int out_size, void* d_ws, size_t ws_size,
                              hipStream_t stream) {
    const int N = NN;

    char* w = (char*)d_ws;
    auto alloc = [&](size_t bytes) {
        void* p = (void*)w;
        w += (bytes + 255) & ~(size_t)255;
        return p;
    };
    int* flags = (int*)alloc(256);
    float* wpool = (float*)alloc((size_t)WTOTAL * 4);
    float* dis = (float*)alloc((size_t)N * 4);
    int* rptr = (int*)alloc((size_t)(N + 1) * 4);
    int* csr_src = (int*)alloc((size_t)EE * 4);
    unsigned* gh = (unsigned*)alloc((size_t)NBK * 256 * 4);
    unsigned* gh2 = (unsigned*)alloc((size_t)NBK * 256 * 4);
    int* bb = (int*)alloc(1024);
    int2* ebkt = (int2*)alloc((size_t)EE * 8);
    float* asrc = (float*)alloc((size_t)N * 4);
    float* adst = (float*)alloc((size_t)N * 4);
    unsigned* bufT = (unsigned*)alloc((size_t)N * 64 * 4);  // bf16 N x 128
    float* bufH = (float*)alloc((size_t)N * 128 * 4);       // fp32 N x 128

    WSrc ws_srcs;
    for (int i = 0; i < 20; ++i) ws_srcs.p[i] = d_in[2 + i];

    const int NB = (N + 255) / 256;
    const int AGG = (N + 3) / 4;
    const int TMB = (N + 63) / 64;
    const int LFB = (N + 63) / 64;
    const int WB = (WTOTAL + 255) / 256;

    k_detect<<<1, 256, 0, stream>>>((const unsigned short*)d_in[0],
                                    (const unsigned int*)d_in[1], flags);
    k_cvt_w<<<WB, 256, 0, stream>>>(ws_srcs, wpool, flags, WTOTAL);
    // bucketed CSR build
    k_hist<<<NBK, 256, 0, stream>>>(d_in[1], gh, flags);
    k_bscan<<<1, 256, 0, stream>>>(gh, gh2, bb, rptr);
    k_scatter<<<NBK, 256, 0, stream>>>(d_in[1], gh2, bb, ebkt, flags);
    k_bucket_csr<<<NBK, 256, 0, stream>>>(ebkt, bb, rptr, dis, csr_src);

    // GCN 1 (x -> t1' = (x@W1)*dis, bf16) : flag-selected input dtype variant
    k_tile_mm<128, 128, 0, true><<<TMB, 256, 0, stream>>>(d_in[0], wpool + OFF_W1, bufT, N, flags, 0, dis);
    k_tile_mm<128, 128, 1, true><<<TMB, 256, 0, stream>>>(d_in[0], wpool + OFF_W1, bufT, N, flags, 1, dis);
    k_agg128<true><<<AGG, 256, 0, stream>>>(bufT, rptr, csr_src, dis, wpool + OFF_B1, bufH, N);
    // GCN 2
    k_tile_mm<128, 64, 1, true><<<TMB, 256, 0, stream>>>(bufH, wpool + OFF_W2, bufT, N, flags, -1, dis);
    k_agg64<true><<<AGG, 256, 0, stream>>>(bufT, rptr, csr_src, dis, wpool + OFF_B2, bufH, N);
    // GCN 3
    k_tile_mm<64, 32, 1, true><<<TMB, 256, 0, stream>>>(bufH, wpool + OFF_W3, bufT, N, flags, -1, dis);
    k_agg32<false><<<AGG, 256, 0, stream>>>(bufT, rptr, csr_src, dis, wpool + OFF_B3, bufH, N);
    // GAT (unscaled)
    k_tile_mm<32, 32, 1, false><<<TMB, 256, 0, stream>>>(bufH, wpool + OFF_GATW, bufT, N, flags, -1, dis);
    k_gat_vec<<<NB, 256, 0, stream>>>(bufT, wpool + OFF_GAS, wpool + OFF_GAD, asrc, adst, N);
    k_gat_agg<<<AGG, 256, 0, stream>>>(bufT, rptr, csr_src, asrc, adst, wpool + OFF_GAB, bufH, N);
    // LSTM + BN + FC (GEMV-style, 8-way j-split)
    k_lstm_fc<<<LFB, 512, 0, stream>>>(bufH, wpool, d_out, flags, N);
}

// Round 4
// 375.625 us; speedup vs baseline: 1.0194x; 1.0104x over previous
//
#include <hip/hip_runtime.h>
#include <hip/hip_bf16.h>
#include <math.h>

typedef __hip_bfloat16 bf16;

#define NN 50000
#define EE 800000
#define EPB 4096   // edges per block (hist/scatter)
#define NBK 196    // dst buckets = ceil(NN/256); also blocks for hist/scatter
#define BCAP 6144  // max edges per bucket (mean 4096, sd ~64)

__device__ __forceinline__ float b2f(bf16 v) { return __bfloat162float(v); }
__device__ __forceinline__ float rcp_(float x) { return __builtin_amdgcn_rcpf(x); }
__device__ __forceinline__ float sigmoidf_(float x) { return rcp_(1.0f + __expf(-x)); }
__device__ __forceinline__ float tanhf_(float x) {
    float xx = fminf(fmaxf(x, -15.0f), 15.0f);
    float e = __expf(2.0f * xx);
    return (e - 1.0f) * rcp_(e + 1.0f);
}
__device__ __forceinline__ float leakyf_(float x) { return x > 0.0f ? x : 0.2f * x; }
__device__ __forceinline__ unsigned short f2bf(float f) {
    unsigned u = __float_as_uint(f);
    unsigned r = (u + 0x7FFFu + ((u >> 16) & 1u)) >> 16;
    return (unsigned short)r;
}
__device__ __forceinline__ unsigned pack2(float a, float b) {
    return (unsigned)f2bf(a) | ((unsigned)f2bf(b) << 16);
}
__device__ __forceinline__ float lo_(unsigned u) { return __uint_as_float(u << 16); }
__device__ __forceinline__ float hi_(unsigned u) { return __uint_as_float(u & 0xFFFF0000u); }

// weight-pool element offsets (fp32 pool in ws)
#define OFF_W1 0
#define OFF_B1 16384
#define OFF_W2 16512
#define OFF_B2 24704
#define OFF_W3 24768
#define OFF_B3 26816
#define OFF_GATW 26848
#define OFF_GAS 27872
#define OFF_GAD 27904
#define OFF_GAB 27936
#define OFF_WIHF 27968
#define OFF_BIHF 36160
#define OFF_BHHF 36416
#define OFF_WIHB 36672
#define OFF_BIHB 44864
#define OFF_BHHB 45120
#define OFF_GAMMA 45376
#define OFF_BETA 45504
#define OFF_FCW 45632
#define OFF_FCB 46912
#define WTOTAL 46922

struct WSrc { const void* p[20]; };

// ---------------- dtype detection ----------------
__global__ void k_detect(const unsigned short* __restrict__ xraw,
                         const unsigned int* __restrict__ eraw, int* __restrict__ flags) {
    __shared__ int f32f, i64f;
    int t = threadIdx.x;
    if (t == 0) { f32f = 0; i64f = 1; }
    __syncthreads();
    for (int i = t; i < 4096; i += 256) {
        unsigned short u = xraw[i];
        int ex = (u >> 7) & 0xFF;
        if (ex >= 0xC0) atomicOr(&f32f, 1);
        if (eraw[2 * i + 1] != 0u) atomicAnd(&i64f, 0);
    }
    __syncthreads();
    if (t == 0) { flags[0] = f32f; flags[1] = i64f; }
}

// ---------------- weight conversion into fp32 pool ----------------
__global__ void k_cvt_w(WSrc srcs, float* __restrict__ dst, const int* __restrict__ flags,
                        int total) {
    constexpr int WOFF[21] = {OFF_W1,   OFF_B1,   OFF_W2,   OFF_B2,   OFF_W3,   OFF_B3,
                              OFF_GATW, OFF_GAS,  OFF_GAD,  OFF_GAB,  OFF_WIHF, OFF_BIHF,
                              OFF_BHHF, OFF_WIHB, OFF_BIHB, OFF_BHHB, OFF_GAMMA, OFF_BETA,
                              OFF_FCW,  OFF_FCB,  WTOTAL};
    int i = blockIdx.x * 256 + threadIdx.x;
    if (i >= total) return;
    int tn = 0;
#pragma unroll
    for (int j = 1; j < 20; ++j)
        if (i >= WOFF[j]) tn = j;
    int local = i - WOFF[tn];
    if (flags[0]) dst[i] = ((const float*)srcs.p[tn])[local];
    else dst[i] = b2f(((const bf16*)srcs.p[tn])[local]);
}

// ---------------- bucketed CSR build ----------------
// P1: per-edge-block histogram over dst buckets (LDS atomics only)
__global__ __launch_bounds__(256) void k_hist(const void* __restrict__ eraw,
                                              unsigned* __restrict__ gh,
                                              const int* __restrict__ flags) {
    __shared__ int h[256];
    int t = threadIdx.x, b = blockIdx.x;
    h[t] = 0;
    __syncthreads();
    int e0 = b * EPB;
    bool i64 = flags[1] != 0;
    for (int i = t; i < EPB; i += 256) {
        int e = e0 + i;
        if (e < EE) {
            int d = i64 ? (int)((const long long*)eraw)[EE + e] : ((const int*)eraw)[EE + e];
            d = min(max(d, 0), NN - 1);
            atomicAdd(&h[d >> 8], 1);
        }
    }
    __syncthreads();
    gh[b * 256 + t] = (unsigned)h[t];
}

// P2: per-(block,bucket) bases + bucket bases (one block; coalesced reads)
__global__ __launch_bounds__(256) void k_bscan(const unsigned* __restrict__ gh,
                                               unsigned* __restrict__ gh2,
                                               int* __restrict__ bb, int* __restrict__ rptr) {
    __shared__ int s[256];
    int t = threadIdx.x;
    unsigned run = 0;
    for (int blk = 0; blk < NBK; ++blk) {
        unsigned v = gh[blk * 256 + t];
        gh2[blk * 256 + t] = run;  // within-bucket offset of this edge-block
        run += v;
    }
    s[t] = (int)run;
    __syncthreads();
    for (int o = 1; o < 256; o <<= 1) {
        int x = (t >= o) ? s[t - o] : 0;
        __syncthreads();
        s[t] += x;
        __syncthreads();
    }
    bb[t] = s[t] - (int)run;  // exclusive: bucket base (bb[196] lands on EE)
    if (t == 0) rptr[NN] = EE;
}

// P3: scatter (src,dst) pairs into bucket-partitioned array (LDS cursors, window writes)
__global__ __launch_bounds__(256) void k_scatter(const void* __restrict__ eraw,
                                                 const unsigned* __restrict__ gh2,
                                                 const int* __restrict__ bb,
                                                 int2* __restrict__ ebkt,
                                                 const int* __restrict__ flags) {
    __shared__ unsigned cur[256];
    int t = threadIdx.x, b = blockIdx.x;
    cur[t] = gh2[b * 256 + t] + (unsigned)bb[t];
    __syncthreads();
    int e0 = b * EPB;
    bool i64 = flags[1] != 0;
    for (int i = t; i < EPB; i += 256) {
        int e = e0 + i;
        if (e < EE) {
            int sn, d;
            if (i64) {
                sn = (int)((const long long*)eraw)[e];
                d = (int)((const long long*)eraw)[EE + e];
            } else {
                sn = ((const int*)eraw)[e];
                d = ((const int*)eraw)[EE + e];
            }
            sn = min(max(sn, 0), NN - 1);
            d = min(max(d, 0), NN - 1);
            unsigned pos = atomicAdd(&cur[d >> 8], 1u);
            if (pos < (unsigned)EE) ebkt[pos] = make_int2(sn, d);
        }
    }
}

// P4: per-bucket LDS counting sort -> coalesced csr_src segment + rptr/dis
__global__ __launch_bounds__(256) void k_bucket_csr(const int2* __restrict__ ebkt,
                                                    const int* __restrict__ bb,
                                                    int* __restrict__ rptr,
                                                    float* __restrict__ dis,
                                                    int* __restrict__ csr_src) {
    __shared__ int hist[256];
    __shared__ int excl[256];
    __shared__ int cur[256];
    __shared__ int sorted[BCAP];
    int t = threadIdx.x, b = blockIdx.x;
    int s0 = bb[b], s1 = bb[b + 1];
    int len = min(s1 - s0, BCAP);
    hist[t] = 0;
    __syncthreads();
    for (int i = t; i < len; i += 256) atomicAdd(&hist[ebkt[s0 + i].y & 255], 1);
    __syncthreads();
    int v = hist[t];
    excl[t] = v;
    __syncthreads();
    for (int o = 1; o < 256; o <<= 1) {
        int x = (t >= o) ? excl[t - o] : 0;
        __syncthreads();
        excl[t] += x;
        __syncthreads();
    }
    int loc = excl[t] - v;  // local exclusive offset
    int node = b * 256 + t;
    if (node < NN) {
        rptr[node] = s0 + loc;
        dis[node] = rsqrtf((float)(v + 1));
    }
    cur[t] = loc;
    __syncthreads();
    for (int i = t; i < len; i += 256) {
        int2 p = ebkt[s0 + i];
        int pos = atomicAdd(&cur[p.y & 255], 1);
        if (pos < BCAP) sorted[pos] = p.x;
    }
    __syncthreads();
    for (int i = t; i < len; i += 256) csr_src[s0 + i] = sorted[i];
}

// ---------------- LDS-tiled GEMM: C(bf16) = A @ W, optional per-node dis scaling --------
template <int KIN, int KOUT, int MODE, bool SCALE>
__global__ __launch_bounds__(256) void k_tile_mm(const void* __restrict__ A,
                                                 const float* __restrict__ W,
                                                 unsigned* __restrict__ C, int n,
                                                 const int* __restrict__ flags, int want,
                                                 const float* __restrict__ dis) {
    if (want >= 0 && flags[0] != want) return;
    constexpr int BK = 32;
    constexpr int AST = BK + 4;
    constexpr int CPT = KOUT / 16;  // 8 / 4 / 2
    __shared__ float As[64 * AST];
    __shared__ float Ws[BK * KOUT];
    int t = threadIdx.x;
    int jc = t & 15;
    int ng = t >> 4;
    int base = blockIdx.x * 64;
    float acc[4][CPT];
#pragma unroll
    for (int i = 0; i < 4; ++i)
#pragma unroll
        for (int c = 0; c < CPT; ++c) acc[i][c] = 0.f;
    int snode = t >> 2;
    int gnode = min(base + snode, n - 1);
    int koff = (t & 3) * 8;
    for (int k0 = 0; k0 < KIN; k0 += BK) {
        {
            const float4* src = (const float4*)(W + k0 * KOUT);
            float4* dst = (float4*)Ws;
#pragma unroll
            for (int p = 0; p < BK * KOUT / 1024; ++p) dst[t + p * 256] = src[t + p * 256];
        }
        if (MODE == 0) {
            const unsigned* xr = (const unsigned*)A + (size_t)gnode * (KIN / 2) + (k0 + koff) / 2;
            unsigned u0 = xr[0], u1 = xr[1], u2 = xr[2], u3 = xr[3];
            float* d = As + snode * AST + koff;
            d[0] = lo_(u0); d[1] = hi_(u0);
            d[2] = lo_(u1); d[3] = hi_(u1);
            d[4] = lo_(u2); d[5] = hi_(u2);
            d[6] = lo_(u3); d[7] = hi_(u3);
        } else {
            const float4* ar = (const float4*)((const float*)A + (size_t)gnode * KIN + k0 + koff);
            float4 v0 = ar[0], v1 = ar[1];
            float4* d = (float4*)(As + snode * AST + koff);
            d[0] = v0;
            d[1] = v1;
        }
        __syncthreads();
#pragma unroll 8
        for (int k = 0; k < BK; ++k) {
            float w[CPT];
            const float* wr = Ws + k * KOUT + jc * CPT;
            if constexpr (CPT >= 4) {
#pragma unroll
                for (int c = 0; c < CPT; c += 4) {
                    float4 wv = *(const float4*)(wr + c);
                    w[c] = wv.x; w[c + 1] = wv.y; w[c + 2] = wv.z; w[c + 3] = wv.w;
                }
            } else {
                float2 wv = *(const float2*)wr;
                w[0] = wv.x; w[1] = wv.y;
            }
            float a0 = As[(ng * 4 + 0) * AST + k];
            float a1 = As[(ng * 4 + 1) * AST + k];
            float a2 = As[(ng * 4 + 2) * AST + k];
            float a3 = As[(ng * 4 + 3) * AST + k];
#pragma unroll
            for (int c = 0; c < CPT; ++c) {
                acc[0][c] += a0 * w[c];
                acc[1][c] += a1 * w[c];
                acc[2][c] += a2 * w[c];
                acc[3][c] += a3 * w[c];
            }
        }
        __syncthreads();
    }
#pragma unroll
    for (int i = 0; i < 4; ++i) {
        int node = base + ng * 4 + i;
        if (node < n) {
            float sc = SCALE ? dis[node] : 1.0f;
            unsigned* cr = C + (size_t)node * (KOUT / 2) + jc * (CPT / 2);
#pragma unroll
            for (int c = 0; c < CPT; c += 2)
                cr[c / 2] = pack2(acc[i][c] * sc, acc[i][c + 1] * sc);
        }
    }
}

// ---------------- GCN agg over pre-scaled t' (t*dis), bf16 gather -> fp32 out -----------
template <bool RELU>
__global__ void k_agg128(const unsigned* __restrict__ t, const int* __restrict__ rptr,
                         const int* __restrict__ csr_src, const float* __restrict__ dis,
                         const float* __restrict__ bias, float* __restrict__ out, int n) {
    int wave = (blockIdx.x * blockDim.x + threadIdx.x) >> 6;
    int lane = threadIdx.x & 63;
    if (wave >= n) return;
    int dst = wave;
    float dd = dis[dst];
    float ax, ay;
    {
        unsigned u = t[(size_t)dst * 64 + lane];
        ax = lo_(u);
        ay = hi_(u);
    }
    int s = __builtin_amdgcn_readfirstlane(max(0, min(rptr[dst], EE)));
    int e = __builtin_amdgcn_readfirstlane(max(s, min(rptr[dst + 1], EE)));
    int j = s;
    for (; j + 8 <= e; j += 8) {
        int i0 = csr_src[j], i1 = csr_src[j + 1], i2 = csr_src[j + 2], i3 = csr_src[j + 3];
        int i4 = csr_src[j + 4], i5 = csr_src[j + 5], i6 = csr_src[j + 6], i7 = csr_src[j + 7];
        unsigned u0 = t[(size_t)i0 * 64 + lane], u1 = t[(size_t)i1 * 64 + lane];
        unsigned u2 = t[(size_t)i2 * 64 + lane], u3 = t[(size_t)i3 * 64 + lane];
        unsigned u4 = t[(size_t)i4 * 64 + lane], u5 = t[(size_t)i5 * 64 + lane];
        unsigned u6 = t[(size_t)i6 * 64 + lane], u7 = t[(size_t)i7 * 64 + lane];
        ax += (lo_(u0) + lo_(u1)) + (lo_(u2) + lo_(u3)) + (lo_(u4) + lo_(u5)) + (lo_(u6) + lo_(u7));
        ay += (hi_(u0) + hi_(u1)) + (hi_(u2) + hi_(u3)) + (hi_(u4) + hi_(u5)) + (hi_(u6) + hi_(u7));
    }
    for (; j + 4 <= e; j += 4) {
        int i0 = csr_src[j], i1 = csr_src[j + 1], i2 = csr_src[j + 2], i3 = csr_src[j + 3];
        unsigned u0 = t[(size_t)i0 * 64 + lane], u1 = t[(size_t)i1 * 64 + lane];
        unsigned u2 = t[(size_t)i2 * 64 + lane], u3 = t[(size_t)i3 * 64 + lane];
        ax += (lo_(u0) + lo_(u1)) + (lo_(u2) + lo_(u3));
        ay += (hi_(u0) + hi_(u1)) + (hi_(u2) + hi_(u3));
    }
    for (; j < e; ++j) {
        unsigned u0 = t[(size_t)csr_src[j] * 64 + lane];
        ax += lo_(u0);
        ay += hi_(u0);
    }
    float2 bv = *(const float2*)(bias + 2 * lane);
    float vx = ax * dd + bv.x;
    float vy = ay * dd + bv.y;
    if (RELU) { vx = fmaxf(vx, 0.f); vy = fmaxf(vy, 0.f); }
    *(float2*)(out + (size_t)dst * 128 + 2 * lane) = make_float2(vx, vy);
}

// F=64: half-wave per edge, explicit 4-batches
template <bool RELU>
__global__ void k_agg64(const unsigned* __restrict__ t, const int* __restrict__ rptr,
                        const int* __restrict__ csr_src, const float* __restrict__ dis,
                        const float* __restrict__ bias, float* __restrict__ out, int n) {
    int wave = (blockIdx.x * blockDim.x + threadIdx.x) >> 6;
    int lane = threadIdx.x & 63;
    if (wave >= n) return;
    int dst = wave;
    int half = lane >> 5, l32 = lane & 31;
    float dd = dis[dst];
    float ax = 0.f, ay = 0.f;
    if (!half) {
        unsigned u = t[(size_t)dst * 32 + l32];
        ax = lo_(u);
        ay = hi_(u);
    }
    int s = max(0, min(rptr[dst], EE));
    int e = max(s, min(rptr[dst + 1], EE));
    int cnt = e - s;
    int pairs = cnt >> 1;
    int p = 0;
    for (; p + 4 <= pairs; p += 4) {
        int jb = s + 2 * p + half;
        int i0 = csr_src[jb], i1 = csr_src[jb + 2], i2 = csr_src[jb + 4], i3 = csr_src[jb + 6];
        unsigned u0 = t[(size_t)i0 * 32 + l32], u1 = t[(size_t)i1 * 32 + l32];
        unsigned u2 = t[(size_t)i2 * 32 + l32], u3 = t[(size_t)i3 * 32 + l32];
        ax += (lo_(u0) + lo_(u1)) + (lo_(u2) + lo_(u3));
        ay += (hi_(u0) + hi_(u1)) + (hi_(u2) + hi_(u3));
    }
    for (; p < pairs; ++p) {
        int i0 = csr_src[s + 2 * p + half];
        unsigned u0 = t[(size_t)i0 * 32 + l32];
        ax += lo_(u0);
        ay += hi_(u0);
    }
    if ((cnt & 1) && !half) {
        unsigned u0 = t[(size_t)csr_src[e - 1] * 32 + l32];
        ax += lo_(u0);
        ay += hi_(u0);
    }
    ax += __shfl_down(ax, 32);
    ay += __shfl_down(ay, 32);
    if (!half) {
        float2 bv = *(const float2*)(bias + 2 * l32);
        float vx = ax * dd + bv.x;
        float vy = ay * dd + bv.y;
        if (RELU) { vx = fmaxf(vx, 0.f); vy = fmaxf(vy, 0.f); }
        *(float2*)(out + (size_t)dst * 64 + 2 * l32) = make_float2(vx, vy);
    }
}

// F=32: quarter-wave per edge, explicit 4-batches
template <bool RELU>
__global__ void k_agg32(const unsigned* __restrict__ t, const int* __restrict__ rptr,
                        const int* __restrict__ csr_src, const float* __restrict__ dis,
                        const float* __restrict__ bias, float* __restrict__ out, int n) {
    int wave = (blockIdx.x * blockDim.x + threadIdx.x) >> 6;
    int lane = threadIdx.x & 63;
    if (wave >= n) return;
    int dst = wave;
    int q = lane >> 4, l16 = lane & 15;
    float dd = dis[dst];
    float ax = 0.f, ay = 0.f;
    if (q == 0) {
        unsigned u = t[(size_t)dst * 16 + l16];
        ax = lo_(u);
        ay = hi_(u);
    }
    int s = max(0, min(rptr[dst], EE));
    int e = max(s, min(rptr[dst + 1], EE));
    int cnt = e - s;
    int quads = cnt >> 2;
    int p = 0;
    for (; p + 4 <= quads; p += 4) {
        int jb = s + 4 * p + q;
        int i0 = csr_src[jb], i1 = csr_src[jb + 4], i2 = csr_src[jb + 8], i3 = csr_src[jb + 12];
        unsigned u0 = t[(size_t)i0 * 16 + l16], u1 = t[(size_t)i1 * 16 + l16];
        unsigned u2 = t[(size_t)i2 * 16 + l16], u3 = t[(size_t)i3 * 16 + l16];
        ax += (lo_(u0) + lo_(u1)) + (lo_(u2) + lo_(u3));
        ay += (hi_(u0) + hi_(u1)) + (hi_(u2) + hi_(u3));
    }
    for (; p < quads; ++p) {
        int i0 = csr_src[s + 4 * p + q];
        unsigned u0 = t[(size_t)i0 * 16 + l16];
        ax += lo_(u0);
        ay += hi_(u0);
    }
    int rem = cnt - 4 * quads;
    if (q < rem) {
        unsigned u0 = t[(size_t)csr_src[s + 4 * quads + q] * 16 + l16];
        ax += lo_(u0);
        ay += hi_(u0);
    }
    ax += __shfl_down(ax, 32);
    ay += __shfl_down(ay, 32);
    ax += __shfl_down(ax, 16);
    ay += __shfl_down(ay, 16);
    if (q == 0) {
        float2 bv = *(const float2*)(bias + 2 * l16);
        float vx = ax * dd + bv.x;
        float vy = ay * dd + bv.y;
        if (RELU) { vx = fmaxf(vx, 0.f); vy = fmaxf(vy, 0.f); }
        *(float2*)(out + (size_t)dst * 32 + 2 * l16) = make_float2(vx, vy);
    }
}

// ---------------- GAT ----------------
__global__ void k_gat_vec(const unsigned* __restrict__ g, const float* __restrict__ a_src,
                          const float* __restrict__ a_dst, float* __restrict__ asrc,
                          float* __restrict__ adst, int n) {
    int i = blockIdx.x * 256 + threadIdx.x;
    if (i >= n) return;
    float s = 0.0f, d = 0.0f;
    const unsigned* gr = g + (size_t)i * 16;
#pragma unroll
    for (int k = 0; k < 16; ++k) {
        unsigned u = gr[k];
        float v0 = lo_(u), v1 = hi_(u);
        s += v0 * a_src[2 * k] + v1 * a_src[2 * k + 1];
        d += v0 * a_dst[2 * k] + v1 * a_dst[2 * k + 1];
    }
    asrc[i] = s;
    adst[i] = d;
}

__global__ void k_gat_agg(const unsigned* __restrict__ g, const int* __restrict__ rptr,
                          const int* __restrict__ csr_src, const float* __restrict__ asrc,
                          const float* __restrict__ adst, const float* __restrict__ gat_b,
                          float* __restrict__ out, int n) {
    int wave = (blockIdx.x * blockDim.x + threadIdx.x) >> 6;
    int lane = threadIdx.x & 63;
    if (wave >= n) return;
    int dst = wave;
    int q = lane >> 4, l16 = lane & 15;
    float ad = adst[dst];
    int s = max(0, min(rptr[dst], EE));
    int e = max(s, min(rptr[dst + 1], EE));
    float ax = 0.f, ay = 0.f, denom = 0.f;
    if (q == 0) {
        float w0 = __expf(fminf(leakyf_(asrc[dst] + ad), 80.f));
        unsigned u = g[(size_t)dst * 16 + l16];
        ax = lo_(u) * w0;
        ay = hi_(u) * w0;
        denom = w0;
    }
    int cnt = e - s;
    int quads = cnt >> 2;
    int p = 0;
    for (; p + 4 <= quads; p += 4) {
        int jb = s + 4 * p + q;
        int i0 = csr_src[jb], i1 = csr_src[jb + 4], i2 = csr_src[jb + 8], i3 = csr_src[jb + 12];
        float a0 = asrc[i0], a1 = asrc[i1], a2 = asrc[i2], a3 = asrc[i3];
        unsigned u0 = g[(size_t)i0 * 16 + l16], u1 = g[(size_t)i1 * 16 + l16];
        unsigned u2 = g[(size_t)i2 * 16 + l16], u3 = g[(size_t)i3 * 16 + l16];
        float w0 = __expf(fminf(leakyf_(a0 + ad), 80.f));
        float w1 = __expf(fminf(leakyf_(a1 + ad), 80.f));
        float w2 = __expf(fminf(leakyf_(a2 + ad), 80.f));
        float w3 = __expf(fminf(leakyf_(a3 + ad), 80.f));
        denom += (w0 + w1) + (w2 + w3);
        ax += lo_(u0) * w0 + lo_(u1) * w1 + lo_(u2) * w2 + lo_(u3) * w3;
        ay += hi_(u0) * w0 + hi_(u1) * w1 + hi_(u2) * w2 + hi_(u3) * w3;
    }
    for (; p < quads; ++p) {
        int i0 = csr_src[s + 4 * p + q];
        float wgt = __expf(fminf(leakyf_(asrc[i0] + ad), 80.f));
        unsigned u0 = g[(size_t)i0 * 16 + l16];
        denom += wgt;
        ax += lo_(u0) * wgt;
        ay += hi_(u0) * wgt;
    }
    int rem = cnt - 4 * quads;
    if (q < rem) {
        int i0 = csr_src[s + 4 * quads + q];
        float wgt = __expf(fminf(leakyf_(asrc[i0] + ad), 80.f));
        unsigned u0 = g[(size_t)i0 * 16 + l16];
        denom += wgt;
        ax += lo_(u0) * wgt;
        ay += hi_(u0) * wgt;
    }
    ax += __shfl_down(ax, 32);
    ay += __shfl_down(ay, 32);
    denom += __shfl_down(denom, 32);
    ax += __shfl_down(ax, 16);
    ay += __shfl_down(ay, 16);
    denom += __shfl_down(denom, 16);
    if (q == 0) {
        float r = rcp_(denom);
        float vx = fmaxf(ax * r + gat_b[2 * l16], 0.f);
        float vy = fmaxf(ay * r + gat_b[2 * l16 + 1], 0.f);
        *(float2*)(out + (size_t)dst * 32 + 2 * l16) = make_float2(vx, vy);
    }
}

// ---------------- fused LSTM + BN + FC: weights-in-VGPR, h broadcast from LDS -----------
// 256 threads = 128 gate-rows x 2 node-groups. Thread owns one (dir,j) row: its 96 weight
// floats live in VGPRs (per-lane, no SGPR budget limit), and it loops over 32 nodes whose
// h rows sit in LDS. All 64 lanes of a wave share the same node -> uniform-address
// ds_read broadcast (conflict-free). r is staged in padded LDS (stride 129 -> 2-way
// bank = free); the FC phase uses wave-uniform jj so fcW comes via scalar loads.
__global__ __launch_bounds__(256, 3) void k_lstm_fc(const float* __restrict__ h,
                                                    const float* __restrict__ wp,
                                                    void* __restrict__ out,
                                                    const int* __restrict__ flags, int n) {
    __shared__ float hs[64 * 32];       // 8 KB: h rows for this block's 64 nodes
    __shared__ float rs[64 * 129];      // 33 KB: r (BN'd LSTM out), padded stride
    __shared__ float ps[4 * 640];       // 10 KB: FC partials
    int t = threadIdx.x;
    int base = blockIdx.x * 64;

    // stage h tile (coalesced float4)
    for (int i = t; i < 512; i += 256) {
        int nd = i >> 3, k4 = i & 7;
        int node = min(base + nd, n - 1);
        ((float4*)hs)[i] = ((const float4*)h)[(size_t)node * 8 + k4];
    }

    int row = t & 127;                              // jj = dir*64 + j
    int grp = t >> 7;                               // node group (wave-uniform)
    int dir = row >> 6, j = row & 63;
    const float* W = wp + (dir ? OFF_WIHB : OFF_WIHF);
    const float* bi = wp + (dir ? OFF_BIHB : OFF_BIHF);
    const float* bh = wp + (dir ? OFF_BHHB : OFF_BHHF);

    // this row's gate weights -> VGPRs (one-time, L2-hot)
    float w_i[32], w_c[32], w_o[32];
    {
        const float4* wip = (const float4*)(W + (size_t)j * 32);
        const float4* wcp = (const float4*)(W + (size_t)(128 + j) * 32);
        const float4* wop = (const float4*)(W + (size_t)(192 + j) * 32);
#pragma unroll
        for (int k4 = 0; k4 < 8; ++k4) {
            float4 a = wip[k4], b = wcp[k4], c = wop[k4];
            w_i[4 * k4 + 0] = a.x; w_i[4 * k4 + 1] = a.y; w_i[4 * k4 + 2] = a.z; w_i[4 * k4 + 3] = a.w;
            w_c[4 * k4 + 0] = b.x; w_c[4 * k4 + 1] = b.y; w_c[4 * k4 + 2] = b.z; w_c[4 * k4 + 3] = b.w;
            w_o[4 * k4 + 0] = c.x; w_o[4 * k4 + 1] = c.y; w_o[4 * k4 + 2] = c.z; w_o[4 * k4 + 3] = c.w;
        }
    }
    float bI = bi[j] + bh[j];
    float bC = bi[128 + j] + bh[128 + j];
    float bO = bi[192 + j] + bh[192 + j];
    float gsc = wp[OFF_GAMMA + row] * rsqrtf(1.0f + 1e-5f);
    float gbe = wp[OFF_BETA + row];

    __syncthreads();

    int slot0 = grp * 32;
    for (int nn = 0; nn < 32; ++nn) {
        const float* hvp = hs + (slot0 + nn) * 32;  // wave-uniform addr -> broadcast
        float ai = bI, ac = bC, ao = bO;
#pragma unroll
        for (int k = 0; k < 32; ++k) {
            float hk = hvp[k];
            ai += hk * w_i[k];
            ac += hk * w_c[k];
            ao += hk * w_o[k];
        }
        float v = sigmoidf_(ao) * tanhf_(sigmoidf_(ai) * tanhf_(ac));
        rs[(slot0 + nn) * 129 + row] = v * gsc + gbe;
    }
    __syncthreads();

    // FC: thread = (node, jj-quarter); jj wave-uniform -> fcW scalar loads
    {
        int nd = t & 63, quarter = t >> 6;
        const float* fcw = wp + OFF_FCW;
        int jbase = quarter * 32;
        float p10[10];
#pragma unroll
        for (int c = 0; c < 10; ++c) p10[c] = 0.f;
#pragma unroll 4
        for (int k = 0; k < 32; ++k) {
            float r = rs[nd * 129 + jbase + k];
#pragma unroll
            for (int c = 0; c < 10; ++c) p10[c] += r * fcw[c * 128 + jbase + k];
        }
#pragma unroll
        for (int c = 0; c < 10; ++c) ps[quarter * 640 + nd * 10 + c] = p10[c];
    }
    __syncthreads();
    bool f32o = flags[0] != 0;
    for (int idx = t; idx < 640; idx += 256) {
        int gnode = base + idx / 10;
        if (gnode < n) {
            int c = idx % 10;
            float v = wp[OFF_FCB + c] + ps[idx] + ps[640 + idx] + ps[1280 + idx] + ps[1920 + idx];
            if (f32o) ((float*)out)[(size_t)base * 10 + idx] = v;
            else ((unsigned short*)out)[(size_t)base * 10 + idx] = f2bf(v);
        }
    }
}

// ---------------- launch ----------------
extern "C" void kernel_launch(void* const* d_in, const int* in_sizes, int n_in,
                              void* d_out, int out_size, void* d_ws, size_t ws_size,
                              hipStream_t stream) {
    const int N = NN;

    char* w = (char*)d_ws;
    auto alloc = [&](size_t bytes) {
        void* p = (void*)w;
        w += (bytes + 255) & ~(size_t)255;
        return p;
    };
    int* flags = (int*)alloc(256);
    float* wpool = (float*)alloc((size_t)WTOTAL * 4);
    float* dis = (float*)alloc((size_t)N * 4);
    int* rptr = (int*)alloc((size_t)(N + 1) * 4);
    int* csr_src = (int*)alloc((size_t)EE * 4);
    unsigned* gh = (unsigned*)alloc((size_t)NBK * 256 * 4);
    unsigned* gh2 = (unsigned*)alloc((size_t)NBK * 256 * 4);
    int* bb = (int*)alloc(1024);
    int2* ebkt = (int2*)alloc((size_t)EE * 8);
    float* asrc = (float*)alloc((size_t)N * 4);
    float* adst = (float*)alloc((size_t)N * 4);
    unsigned* bufT = (unsigned*)alloc((size_t)N * 64 * 4);  // bf16 N x 128
    float* bufH = (float*)alloc((size_t)N * 128 * 4);       // fp32 N x 128

    WSrc ws_srcs;
    for (int i = 0; i < 20; ++i) ws_srcs.p[i] = d_in[2 + i];

    const int NB = (N + 255) / 256;
    const int AGG = (N + 3) / 4;
    const int TMB = (N + 63) / 64;
    const int LFB = (N + 63) / 64;
    const int WB = (WTOTAL + 255) / 256;

    k_detect<<<1, 256, 0, stream>>>((const unsigned short*)d_in[0],
                                    (const unsigned int*)d_in[1], flags);
    k_cvt_w<<<WB, 256, 0, stream>>>(ws_srcs, wpool, flags, WTOTAL);
    // bucketed CSR build
    k_hist<<<NBK, 256, 0, stream>>>(d_in[1], gh, flags);
    k_bscan<<<1, 256, 0, stream>>>(gh, gh2, bb, rptr);
    k_scatter<<<NBK, 256, 0, stream>>>(d_in[1], gh2, bb, ebkt, flags);
    k_bucket_csr<<<NBK, 256, 0, stream>>>(ebkt, bb, rptr, dis, csr_src);

    // GCN 1 (x -> t1' = (x@W1)*dis, bf16) : flag-selected input dtype variant
    k_tile_mm<128, 128, 0, true><<<TMB, 256, 0, stream>>>(d_in[0], wpool + OFF_W1, bufT, N, flags, 0, dis);
    k_tile_mm<128, 128, 1, true><<<TMB, 256, 0, stream>>>(d_in[0], wpool + OFF_W1, bufT, N, flags, 1, dis);
    k_agg128<true><<<AGG, 256, 0, stream>>>(bufT, rptr, csr_src, dis, wpool + OFF_B1, bufH, N);
    // GCN 2
    k_tile_mm<128, 64, 1, true><<<TMB, 256, 0, stream>>>(bufH, wpool + OFF_W2, bufT, N, flags, -1, dis);
    k_agg64<true><<<AGG, 256, 0, stream>>>(bufT, rptr, csr_src, dis, wpool + OFF_B2, bufH, N);
    // GCN 3
    k_tile_mm<64, 32, 1, true><<<TMB, 256, 0, stream>>>(bufH, wpool + OFF_W3, bufT, N, flags, -1, dis);
    k_agg32<false><<<AGG, 256, 0, stream>>>(bufT, rptr, csr_src, dis, wpool + OFF_B3, bufH, N);
    // GAT (unscaled)
    k_tile_mm<32, 32, 1, false><<<TMB, 256, 0, stream>>>(bufH, wpool + OFF_GATW, bufT, N, flags, -1, dis);
    k_gat_vec<<<NB, 256, 0, stream>>>(bufT, wpool + OFF_GAS, wpool + OFF_GAD, asrc, adst, N);
    k_gat_agg<<<AGG, 256, 0, stream>>>(bufT, rptr, csr_src, asrc, adst, wpool + OFF_GAB, bufH, N);
    // LSTM + BN + FC (weights-in-VGPR)
    k_lstm_fc<<<LFB, 256, 0, stream>>>(bufH, wpool, d_out, flags, N);
}